// Round 9
// baseline (3666.670 us; speedup 1.0000x reference)
//
#include <hip/hip_runtime.h>
#include <math.h>
#include <stdint.h>

// ---- problem dims ----
constexpr int Bsz = 512, Kf = 36, Dd = 2048, Aa = 512, Hh = 512, Em = 300;
constexpr int Vv = 10000, TSTEPS = 19, BOS = 1;
constexpr int K1 = 832;          // padded Em+Hh (812 -> 832)
constexpr int K2 = 1536;         // h1|ctx|h2
constexpr int VvP = 10112;       // vocab rows padded (158 tiles of 64)
constexpr int NTL = VvP / 64;    // 158 logit tiles
constexpr float SPLIT_S  = 2048.0f;
constexpr float SPLIT_IS = 1.0f / 2048.0f;

#define CDIV(a,b) (((a)+(b)-1)/(b))

typedef _Float16 f16x8 __attribute__((ext_vector_type(8)));
typedef float    f32x4 __attribute__((ext_vector_type(4)));

typedef const unsigned int GU __attribute__((address_space(1)));
typedef unsigned int       LU __attribute__((address_space(3)));

__device__ __forceinline__ void gload16(const void* g, void* l) {
    __builtin_amdgcn_global_load_lds((GU*)g, (LU*)l, 16, 0, 0);
}

template<int N> __device__ __forceinline__ void wait_vm() {
    if constexpr (N == 0)       asm volatile("s_waitcnt vmcnt(0)" ::: "memory");
    else if constexpr (N == 4)  asm volatile("s_waitcnt vmcnt(4)" ::: "memory");
    else if constexpr (N == 6)  asm volatile("s_waitcnt vmcnt(6)" ::: "memory");
    else if constexpr (N == 8)  asm volatile("s_waitcnt vmcnt(8)" ::: "memory");
    else if constexpr (N == 12) asm volatile("s_waitcnt vmcnt(12)" ::: "memory");
    else if constexpr (N == 16) asm volatile("s_waitcnt vmcnt(16)" ::: "memory");
    else static_assert(N == 0, "unsupported vmcnt literal");
}
#define WAIT_LGKM asm volatile("s_waitcnt lgkmcnt(0)" ::: "memory")
#define SB0 __builtin_amdgcn_sched_barrier(0)
#define BAR __builtin_amdgcn_s_barrier()

__device__ __forceinline__ float sigm(float v) { return 1.0f / (1.0f + expf(-v)); }

__device__ __forceinline__ void wsplit(_Float16* __restrict__ hi, _Float16* __restrict__ lo,
                                       size_t idx, float v) {
    _Float16 h = (_Float16)v;
    hi[idx] = h;
    lo[idx] = (_Float16)((v - (float)h) * SPLIT_S);
}

// ============================================================
// Split-fp16 MFMA GEMM. C[M,N] = A[M,K] @ B[N,K]^T (+bias1+bias2+addC).
// AF32 (DEPTH must be 2): A fp32, reg-prefetch + in-kernel split (K/BK even).
// !AF32: A pre-split, global_load_lds, DEPTH buffers, DEPTH-1 in flight.
// PAD: extra halfs per k-plane. MUST be 0 when BM or BN == 32 (wave-linear
// global_load_lds dest spans two planes there; PAD=0 makes layout linear).
// SWZ: 1D grid + XCD-bijective swizzle (n fastest, gxn n-tiles); else 2D grid.
// EPI: 0 = store C; 3 = per-tile argmax -> candV/candI (no C store);
//      4 = store C AND split pair.
// ============================================================
template<int BM, int BN, int BK, int DEPTH, bool AF32, bool SWZ, int OCC, int EPI, int PAD>
__global__ __launch_bounds__(256, OCC)
void gemm_sp(const float* __restrict__ Af,
             const _Float16* __restrict__ Ahi, const _Float16* __restrict__ Alo, int lda,
             const _Float16* __restrict__ Bhi, const _Float16* __restrict__ Blo, int ldb,
             float* __restrict__ C, int ldc, int N, int K,
             const float* __restrict__ bias1, const float* __restrict__ bias2,
             const float* __restrict__ addC, int gxn,
             _Float16* __restrict__ pairH, _Float16* __restrict__ pairL,
             float* __restrict__ candV, int* __restrict__ candI, int ntl)
{
    constexpr int WM = BM / 2, WN = BN / 2;
    constexpr int MF = WM / 16, NF = WN / 16;
    constexpr int PA  = BK / 8;
    constexpr int PSA = BM * 8 + PAD;
    constexpr int PSB = BN * 8 + PAD;
    static_assert(PAD == 0 || (BM >= 64 && BN >= 64), "PAD needs wave-aligned planes");
    constexpr int SZA = PA * PSA, SZB = PA * PSB;
    constexpr int OAH = 0, OAL = SZA, OBH = 2 * SZA, OBL = 2 * SZA + SZB;
    constexpr int BUF = 2 * SZA + 2 * SZB;
    constexpr int NCHA = BM * BK / 2048;
    constexpr int NCHB = BN * BK / 2048;
    static_assert(NCHA >= 1 && NCHB >= 1, "tile too small for 256-thread stage");
    constexpr int LW = 2 * NCHA + 2 * NCHB;     // vm ops per thread per tile
    static_assert((DEPTH & (DEPTH - 1)) == 0, "DEPTH pow2");
    static_assert(!AF32 || DEPTH == 2, "AF32 path is double-buffered");
    __shared__ _Float16 sm[DEPTH * BUF];

    int mt, nt;
    if constexpr (SWZ) {
        const int nwg = gridDim.x;
        const int cpx = nwg >> 3;
        const int orig = blockIdx.x;
        const int lid = (orig & 7) * cpx + (orig >> 3);
        nt = lid % gxn; mt = lid / gxn;
    } else {
        nt = blockIdx.x; mt = blockIdx.y;
    }
    const int m0 = mt * BM, n0 = nt * BN;

    const int t    = threadIdx.x;
    const int lane = t & 63;
    const int w    = t >> 6;
    const int wr   = w >> 1, wc = w & 1;
    const int l15  = lane & 15, l4 = lane >> 4;

    f32x4 acch[MF][NF];
    f32x4 accm[MF][NF];
    #pragma unroll
    for (int m = 0; m < MF; ++m)
        #pragma unroll
        for (int n = 0; n < NF; ++n) {
            acch[m][n] = (f32x4){0.f, 0.f, 0.f, 0.f};
            accm[m][n] = (f32x4){0.f, 0.f, 0.f, 0.f};
        }

    const int nkt = K / BK;

    auto stageB = [&](int bufo, int kt) {
        #pragma unroll
        for (int i = 0; i < NCHB; ++i) {
            const int q  = i * 256 + t;
            const int p  = q / BN, r = q % BN;
            const int qw = i * 256 + (t & ~63);
            const int pu = qw / BN, ru = qw % BN;
            const size_t goff = (size_t)(n0 + r) * ldb + kt * BK + p * 8;
            gload16(Bhi + goff, &sm[bufo + OBH + pu * PSB + ru * 8]);
            gload16(Blo + goff, &sm[bufo + OBL + pu * PSB + ru * 8]);
        }
    };
    auto stageA16 = [&](int bufo, int kt) {
        #pragma unroll
        for (int i = 0; i < NCHA; ++i) {
            const int q  = i * 256 + t;
            const int p  = q / BM, r = q % BM;
            const int qw = i * 256 + (t & ~63);
            const int pu = qw / BM, ru = qw % BM;
            const size_t goff = (size_t)(m0 + r) * lda + kt * BK + p * 8;
            gload16(Ahi + goff, &sm[bufo + OAH + pu * PSA + ru * 8]);
            gload16(Alo + goff, &sm[bufo + OAL + pu * PSA + ru * 8]);
        }
    };
    auto issueA = [&](float4 (&rd)[NCHA][2], int kt) {
        #pragma unroll
        for (int i = 0; i < NCHA; ++i) {
            const int q = i * 256 + t;
            const int p = q / BM, r = q % BM;
            const float* src = Af + (size_t)(m0 + r) * lda + kt * BK + p * 8;
            rd[i][0] = *(const float4*)src;
            rd[i][1] = *(const float4*)(src + 4);
        }
    };
    auto writeA = [&](int bufo, float4 (&rd)[NCHA][2]) {
        #pragma unroll
        for (int i = 0; i < NCHA; ++i) {
            const int q = i * 256 + t;
            const int p = q / BM, r = q % BM;
            const float f[8] = {rd[i][0].x, rd[i][0].y, rd[i][0].z, rd[i][0].w,
                                rd[i][1].x, rd[i][1].y, rd[i][1].z, rd[i][1].w};
            f16x8 hi, lo;
            #pragma unroll
            for (int j = 0; j < 8; ++j) {
                _Float16 h = (_Float16)f[j];
                hi[j] = h;
                lo[j] = (_Float16)((f[j] - (float)h) * SPLIT_S);
            }
            *(f16x8*)&sm[bufo + OAH + p * PSA + r * 8] = hi;
            *(f16x8*)&sm[bufo + OAL + p * PSA + r * 8] = lo;
        }
    };
    auto compute = [&](int bufo) {
        #pragma unroll
        for (int s = 0; s < BK / 32; ++s) {
            f16x8 ah[MF], al[MF], bh[NF], bl[NF];
            const int pl = s * 4 + l4;
            #pragma unroll
            for (int m = 0; m < MF; ++m) {
                const int row = wr * WM + m * 16 + l15;
                ah[m] = *(const f16x8*)&sm[bufo + OAH + pl * PSA + row * 8];
                al[m] = *(const f16x8*)&sm[bufo + OAL + pl * PSA + row * 8];
            }
            #pragma unroll
            for (int n = 0; n < NF; ++n) {
                const int row = wc * WN + n * 16 + l15;
                bh[n] = *(const f16x8*)&sm[bufo + OBH + pl * PSB + row * 8];
                bl[n] = *(const f16x8*)&sm[bufo + OBL + pl * PSB + row * 8];
            }
            #pragma unroll
            for (int m = 0; m < MF; ++m)
                #pragma unroll
                for (int n = 0; n < NF; ++n) {
                    acch[m][n] = __builtin_amdgcn_mfma_f32_16x16x32_f16(ah[m], bh[n], acch[m][n], 0, 0, 0);
                    accm[m][n] = __builtin_amdgcn_mfma_f32_16x16x32_f16(ah[m], bl[n], accm[m][n], 0, 0, 0);
                    accm[m][n] = __builtin_amdgcn_mfma_f32_16x16x32_f16(al[m], bh[n], accm[m][n], 0, 0, 0);
                }
        }
    };

    if constexpr (AF32) {
        float4 rA[NCHA][2], rB[NCHA][2];
        issueA(rA, 0); stageB(0, 0);
        for (int kt = 0; kt < nkt; kt += 2) {
            issueA(rB, kt + 1); stageB(BUF, kt + 1);
            wait_vm<LW>(); SB0;
            writeA(0, rA);
            WAIT_LGKM; SB0;
            BAR; SB0;
            compute(0);
            SB0; WAIT_LGKM; BAR; SB0;
            if (kt + 2 < nkt) { issueA(rA, kt + 2); stageB(0, kt + 2); wait_vm<LW>(); }
            else              { wait_vm<0>(); }
            SB0;
            writeA(BUF, rB);
            WAIT_LGKM; SB0;
            BAR; SB0;
            compute(BUF);
            SB0; WAIT_LGKM; BAR; SB0;
        }
    } else {
        #pragma unroll
        for (int d = 0; d < DEPTH - 1; ++d) { stageA16(d * BUF, d); stageB(d * BUF, d); }
        for (int kt = 0; kt < nkt; ++kt) {
            const int bc = (kt & (DEPTH - 1)) * BUF;
            if (kt + DEPTH - 1 < nkt) {
                const int bn = ((kt + DEPTH - 1) & (DEPTH - 1)) * BUF;
                stageA16(bn, kt + DEPTH - 1); stageB(bn, kt + DEPTH - 1);
                wait_vm<(DEPTH - 1) * LW>();
            } else {
                const int rem = nkt - 1 - kt;   // tiles still in flight past current
                if constexpr (DEPTH >= 4) {
                    if (rem >= 2)      wait_vm<2 * LW>();
                    else if (rem == 1) wait_vm<LW>();
                    else               wait_vm<0>();
                } else {
                    if (rem >= 1) wait_vm<LW>(); else wait_vm<0>();
                }
            }
            SB0;
            BAR; SB0;
            compute(bc);
            SB0; WAIT_LGKM; BAR; SB0;
        }
    }

    // ---- epilogue ----
    if constexpr (EPI == 0 || EPI == 4) {
        #pragma unroll
        for (int m = 0; m < MF; ++m) {
            const int rowb = m0 + wr * WM + m * 16 + l4 * 4;
            #pragma unroll
            for (int n = 0; n < NF; ++n) {
                const int col = n0 + wc * WN + n * 16 + l15;
                if (col < N) {
                    float bb = 0.f;
                    if (bias1) bb += bias1[col];
                    if (bias2) bb += bias2[col];
                    #pragma unroll
                    for (int r = 0; r < 4; ++r) {
                        const size_t idx = (size_t)(rowb + r) * ldc + col;
                        float v = acch[m][n][r] + accm[m][n][r] * SPLIT_IS + bb;
                        if (addC) v += addC[idx];
                        C[idx] = v;
                        if constexpr (EPI == 4) wsplit(pairH, pairL, idx, v);
                    }
                }
            }
        }
    } else {
        // EPI 3: per-row block-local argmax (global col idx, first-max ties)
        float* sEv = reinterpret_cast<float*>(&sm[0]);
        int*   sEi = reinterpret_cast<int*>(&sm[0]) + 2 * BM;
        float bv[MF][4];
        int   bix[MF][4];
        #pragma unroll
        for (int m = 0; m < MF; ++m)
            #pragma unroll
            for (int r = 0; r < 4; ++r) { bv[m][r] = -INFINITY; bix[m][r] = 0x7fffffff; }
        #pragma unroll
        for (int m = 0; m < MF; ++m)
            #pragma unroll
            for (int r = 0; r < 4; ++r)
                #pragma unroll
                for (int n = 0; n < NF; ++n) {   // n ascending = col ascending
                    const int col = n0 + wc * WN + n * 16 + l15;
                    if (col < N) {
                        const float x = acch[m][n][r] + accm[m][n][r] * SPLIT_IS + bias1[col];
                        if (x > bv[m][r]) { bv[m][r] = x; bix[m][r] = col; }
                    }
                }
        #pragma unroll
        for (int mask = 1; mask < 16; mask <<= 1) {
            #pragma unroll
            for (int m = 0; m < MF; ++m)
                #pragma unroll
                for (int r = 0; r < 4; ++r) {
                    const float ov = __shfl_xor(bv[m][r], mask);
                    const int   oi = __shfl_xor(bix[m][r], mask);
                    if (ov > bv[m][r] || (ov == bv[m][r] && oi < bix[m][r])) {
                        bv[m][r] = ov; bix[m][r] = oi;
                    }
                }
        }
        __syncthreads();   // K-loop LDS reads done before reuse
        if (l15 == 0) {
            #pragma unroll
            for (int m = 0; m < MF; ++m)
                #pragma unroll
                for (int r = 0; r < 4; ++r) {
                    const int rl = wr * WM + m * 16 + l4 * 4 + r;
                    sEv[wc * BM + rl] = bv[m][r];
                    sEi[wc * BM + rl] = bix[m][r];
                }
        }
        __syncthreads();
        if (t < BM) {
            float v0 = sEv[t]; int i0 = sEi[t];
            const float v1 = sEv[BM + t]; const int i1 = sEi[BM + t];
            if (v1 > v0 || (v1 == v0 && i1 < i0)) { v0 = v1; i0 = i1; }
            candV[(size_t)(m0 + t) * ntl + nt] = v0;
            candI[(size_t)(m0 + t) * ntl + nt] = i0;
        }
    }
}

// ============================================================
// weight split-convert
// ============================================================
__global__ __launch_bounds__(256)
void split_convert(const float* __restrict__ src, int srcld, int validR,
                   _Float16* __restrict__ dhi, _Float16* __restrict__ dlo,
                   int dstld, int coloff, int R, int C)
{
    const int total = R * C;
    for (int i = blockIdx.x * 256 + threadIdx.x; i < total; i += gridDim.x * 256) {
        const int r = i / C, c = i % C;
        const float v = (r < validR) ? src[(size_t)r * srcld + c] : 0.f;
        wsplit(dhi, dlo, (size_t)r * dstld + coloff + c, v);
    }
}

__global__ __launch_bounds__(256)
void init_kernel(_Float16* __restrict__ a1h, _Float16* __restrict__ a1l,
                 _Float16* __restrict__ a2h, _Float16* __restrict__ a2l,
                 float* __restrict__ c1, float* __restrict__ c2,
                 const float* __restrict__ E)
{
    const int idx = blockIdx.x * 256 + threadIdx.x;   // grid covers 512*1536
    if (idx < Bsz * K1) {
        const int col = idx % K1;
        const float v = (col < Em) ? E[(size_t)BOS * Em + col] : 0.f;
        wsplit(a1h, a1l, idx, v);
    }
    if (idx < Bsz * K2) wsplit(a2h, a2l, idx, 0.f);
    if (idx < Bsz * Hh) { c1[idx] = 0.f; c2[idx] = 0.f; }
}

// f_mean (fp32 + split pair)
__global__ __launch_bounds__(256)
void fmean_kernel(const float* __restrict__ f_att, float* __restrict__ f_mean,
                  _Float16* __restrict__ fmh, _Float16* __restrict__ fml)
{
    const int b = blockIdx.x;
    for (int a = threadIdx.x; a < Aa; a += 256) {
        float s = 0.f;
        for (int k = 0; k < Kf; ++k) s += f_att[((size_t)b * Kf + k) * Aa + a];
        const float v = s * (1.0f / 36.0f);
        f_mean[(size_t)b * Aa + a] = v;
        wsplit(fmh, fml, (size_t)b * Aa + a, v);
    }
}

// LSTM cell elementwise; h written as fp16 split pair(s).
__global__ __launch_bounds__(256)
void lstm_cell_kernel(const float* __restrict__ g, float* __restrict__ c,
                      _Float16* __restrict__ hhi, _Float16* __restrict__ hlo,
                      int hld, int hoff,
                      _Float16* __restrict__ h2hi, _Float16* __restrict__ h2lo,
                      int h2ld, int h2off)
{
    const int idx = blockIdx.x * 256 + threadIdx.x;   // < B*H
    const int b = idx >> 9, h = idx & 511;
    const float* gb = g + (size_t)b * 2048;
    const float gi = gb[h], gf = gb[512 + h], gc = gb[1024 + h], go = gb[1536 + h];
    const float cv = sigm(gf) * c[idx] + sigm(gi) * tanhf(gc);
    c[idx] = cv;
    const float hv = sigm(go) * tanhf(cv);
    wsplit(hhi, hlo, (size_t)b * hld + hoff + h, hv);
    if (h2hi) wsplit(h2hi, h2lo, (size_t)b * h2ld + h2off + h, hv);
}

// Fused attention: e scores (tanh dot with GEMM-produced q), softmax over k,
// ctx -> A2 cols [512,1024). One block per b.
__global__ __launch_bounds__(256)
void attn_fused(const float* __restrict__ att_f, const float* __restrict__ q,
                const float* __restrict__ wa2, const float* __restrict__ ba2,
                const float* __restrict__ f_att,
                _Float16* __restrict__ a2h, _Float16* __restrict__ a2l)
{
    const int b = blockIdx.x, tid = threadIdx.x;
    const int w = tid >> 6, lane = tid & 63;
    __shared__ float se[Kf];
    __shared__ float wk[Kf];
    const float* pq = q + (size_t)b * Aa;
    for (int k = w; k < Kf; k += 4) {
        const float* pf = att_f + ((size_t)b * Kf + k) * Aa;
        float s = 0.f;
        #pragma unroll
        for (int j = 0; j < Aa; j += 64) {
            const int a = j + lane;
            s += tanhf(pf[a] + pq[a]) * wa2[a];
        }
        #pragma unroll
        for (int off = 32; off; off >>= 1) s += __shfl_down(s, off);
        if (lane == 0) se[k] = s + ba2[0];
    }
    __syncthreads();
    if (tid < Kf) {
        float mx = -INFINITY;
        for (int k = 0; k < Kf; ++k) mx = fmaxf(mx, se[k]);
        float ssum = 0.f;
        for (int k = 0; k < Kf; ++k) ssum += expf(se[k] - mx);
        wk[tid] = expf(se[tid] - mx) / ssum;
    }
    __syncthreads();
    for (int a = tid; a < Aa; a += 256) {
        float acc = 0.f;
        for (int k = 0; k < Kf; ++k)
            acc = fmaf(wk[k], f_att[((size_t)b * Kf + k) * Aa + a], acc);
        wsplit(a2h, a2l, (size_t)b * K2 + Hh + a, acc);
    }
}

// final argmax over per-tile candidates (first-max via min-index tie-break)
// + embed gather -> A1 split cols [0,300)
__global__ __launch_bounds__(256)
void argmax_embed_kernel(const float* __restrict__ candV, const int* __restrict__ candI,
                         const float* __restrict__ E,
                         _Float16* __restrict__ a1h, _Float16* __restrict__ a1l,
                         int* __restrict__ out, int t, int ntl)
{
    const int b = blockIdx.x;
    const int tid = threadIdx.x;
    __shared__ float sv[256];
    __shared__ int   si[256];
    float bvv = -INFINITY; int bii = 0x7fffffff;
    if (tid < ntl) { bvv = candV[(size_t)b * ntl + tid]; bii = candI[(size_t)b * ntl + tid]; }
    sv[tid] = bvv; si[tid] = bii;
    __syncthreads();
    for (int s = 128; s > 0; s >>= 1) {
        if (tid < s) {
            const float v2 = sv[tid + s];
            const int   i2 = si[tid + s];
            if (v2 > sv[tid] || (v2 == sv[tid] && i2 < si[tid])) { sv[tid] = v2; si[tid] = i2; }
        }
        __syncthreads();
    }
    const int idx = si[0];
    if (tid == 0) out[(size_t)b * TSTEPS + t] = idx;
    for (int d = tid; d < Em; d += 256)
        wsplit(a1h, a1l, (size_t)b * K1 + d, E[(size_t)idx * Em + d]);
}

// ============================================================
// host side
// ============================================================
static inline void conv(hipStream_t s, const float* src, int srcld, int validR,
                        _Float16* dhi, _Float16* dlo, int dstld, int coloff, int R, int C)
{
    int blocks = CDIV(R * C, 256); if (blocks > 2048) blocks = 2048;
    split_convert<<<dim3(blocks), dim3(256), 0, s>>>(src, srcld, validR, dhi, dlo, dstld, coloff, R, C);
}

extern "C" void kernel_launch(void* const* d_in, const int* in_sizes, int n_in,
                              void* d_out, int out_size, void* d_ws, size_t ws_size,
                              hipStream_t stream)
{
    const float* feats = (const float*)d_in[0];
    const float* Wp    = (const float*)d_in[1];
    const float* bp    = (const float*)d_in[2];
    const float* E     = (const float*)d_in[3];
    const float* Wih1  = (const float*)d_in[4];
    const float* Whh1  = (const float*)d_in[5];
    const float* bih1  = (const float*)d_in[6];
    const float* bhh1  = (const float*)d_in[7];
    const float* Wih2  = (const float*)d_in[8];
    const float* Whh2  = (const float*)d_in[9];
    const float* bih2  = (const float*)d_in[10];
    const float* bhh2  = (const float*)d_in[11];
    const float* Wa1   = (const float*)d_in[12];
    const float* ba1   = (const float*)d_in[13];
    const float* wa2   = (const float*)d_in[14];
    const float* ba2   = (const float*)d_in[15];
    const float* Wo    = (const float*)d_in[16];
    const float* bo    = (const float*)d_in[17];
    int* out = (int*)d_out;
    (void)in_sizes; (void)n_in; (void)out_size; (void)ws_size;

    uint8_t* w = (uint8_t*)d_ws;
    size_t off = 0;
    auto alloc = [&](size_t bytes) { void* p = w + off; off = (off + bytes + 255) & ~(size_t)255; return p; };

    float*     f_att  = (float*)alloc(18432ull * 512 * 4);
    float*     att_f  = (float*)alloc(18432ull * 512 * 4);
    float*     f_mean = (float*)alloc(512ull * 512 * 4);
    _Float16*  fmh    = (_Float16*)alloc(512ull * 512 * 2);
    _Float16*  fml    = (_Float16*)alloc(512ull * 512 * 2);
    _Float16*  wph    = (_Float16*)alloc(512ull * 2048 * 2);
    _Float16*  wpl    = (_Float16*)alloc(512ull * 2048 * 2);
    _Float16*  w1ph   = (_Float16*)alloc(2048ull * K1 * 2);
    _Float16*  w1pl   = (_Float16*)alloc(2048ull * K1 * 2);
    _Float16*  w1ch   = (_Float16*)alloc(2048ull * 512 * 2);
    _Float16*  w1cl   = (_Float16*)alloc(2048ull * 512 * 2);
    _Float16*  w2ph   = (_Float16*)alloc(2048ull * K2 * 2);
    _Float16*  w2pl   = (_Float16*)alloc(2048ull * K2 * 2);
    _Float16*  wahh   = (_Float16*)alloc(512ull * 512 * 2);
    _Float16*  wahl   = (_Float16*)alloc(512ull * 512 * 2);
    _Float16*  wafh   = (_Float16*)alloc(512ull * 512 * 2);
    _Float16*  wafl   = (_Float16*)alloc(512ull * 512 * 2);
    _Float16*  woh    = (_Float16*)alloc((size_t)VvP * 512 * 2);
    _Float16*  wol    = (_Float16*)alloc((size_t)VvP * 512 * 2);
    float*     g1c    = (float*)alloc(512ull * 2048 * 4);
    _Float16*  a1h    = (_Float16*)alloc(512ull * K1 * 2);
    _Float16*  a1l    = (_Float16*)alloc(512ull * K1 * 2);
    _Float16*  a2h    = (_Float16*)alloc(512ull * K2 * 2);
    _Float16*  a2l    = (_Float16*)alloc(512ull * K2 * 2);
    float*     c1     = (float*)alloc(512ull * 512 * 4);
    float*     c2     = (float*)alloc(512ull * 512 * 4);
    float*     gbuf   = (float*)alloc(512ull * 2048 * 4);
    float*     qbuf   = (float*)alloc(512ull * 512 * 4);
    float*     candV  = (float*)alloc(512ull * NTL * 4);
    int*       candI  = (int*)alloc(512ull * NTL * 4);

    // ---- weight conversions ----
    conv(stream, Wp,        Dd,      512,  wph,  wpl,  2048, 0,    512,  2048);
    conv(stream, Wih1,      Em + Aa, 2048, w1ph, w1pl, K1,   0,    2048, Em);
    conv(stream, Whh1,      Hh,      2048, w1ph, w1pl, K1,   Em,   2048, 512);
    conv(stream, Wih1,      Em + Aa, 0,    w1ph, w1pl, K1,   812,  2048, 20);   // zero pad
    conv(stream, Wih1 + Em, Em + Aa, 2048, w1ch, w1cl, 512,  0,    2048, 512);
    conv(stream, Wih2,      Hh + Aa, 2048, w2ph, w2pl, K2,   0,    2048, 1024);
    conv(stream, Whh2,      Hh,      2048, w2ph, w2pl, K2,   1024, 2048, 512);
    conv(stream, Wa1,       Hh + Aa, 512,  wahh, wahl, 512,  0,    512,  512);
    conv(stream, Wa1 + Hh,  Hh + Aa, 512,  wafh, wafl, 512,  0,    512,  512);
    conv(stream, Wo,        Hh,      Vv,   woh,  wol,  512,  0,    VvP,  512);

    init_kernel<<<dim3(CDIV(Bsz * K2, 256)), dim3(256), 0, stream>>>(a1h, a1l, a2h, a2l, c1, c2, E);

    // ---- precompute (r7-exact configs) ----
    // f_att = feats @ Wp^T + bp   (M=18432 N=512 K=2048; swizzled, NFAST)
    gemm_sp<128, 64, 32, 2, true, true, 2, 0, 8><<<dim3(1152), 256, 0, stream>>>(
        feats, nullptr, nullptr, Dd, wph, wpl, 2048, f_att, 512, 512, 2048,
        bp, nullptr, nullptr, 8, nullptr, nullptr, nullptr, nullptr, 0);
    fmean_kernel<<<dim3(Bsz), dim3(256), 0, stream>>>(f_att, f_mean, fmh, fml);
    // g1c = f_mean @ Wih1[:,Em:]^T + bih1 + bhh1   (512 x 2048, K=512)
    gemm_sp<64, 64, 64, 2, false, false, 1, 0, 8><<<dim3(32, 8), 256, 0, stream>>>(
        nullptr, fmh, fml, 512, w1ch, w1cl, 512, g1c, 2048, 2048, 512,
        bih1, bhh1, nullptr, 0, nullptr, nullptr, nullptr, nullptr, 0);
    // att_f = f_att @ Wa1[:,H:]^T + ba1   (18432 x 512, K=512; swizzled, NFAST)
    gemm_sp<128, 64, 32, 2, true, true, 2, 0, 8><<<dim3(1152), 256, 0, stream>>>(
        f_att, nullptr, nullptr, 512, wafh, wafl, 512, att_f, 512, 512, 512,
        ba1, nullptr, nullptr, 8, nullptr, nullptr, nullptr, nullptr, 0);

    // ---- decode loop (8 launches/step) ----
    for (int t = 0; t < TSTEPS; ++t) {
        // g1 = A1 @ W1p^T + g1c   (512 x 2048, K=832; BN=32 -> 512 blocks)
        gemm_sp<64, 32, 64, 2, false, false, 3, 0, 0><<<dim3(64, 8), 256, 0, stream>>>(
            nullptr, a1h, a1l, K1, w1ph, w1pl, K1, gbuf, 2048, 2048, K1,
            nullptr, nullptr, g1c, 0, nullptr, nullptr, nullptr, nullptr, 0);
        lstm_cell_kernel<<<dim3(Bsz * Hh / 256), dim3(256), 0, stream>>>(
            gbuf, c1, a2h, a2l, K2, 0, a1h, a1l, K1, Em);
        // q = h1 @ Wa1[:,:H]^T   (512 x 512, K=512; BN=32)
        gemm_sp<64, 32, 64, 2, false, false, 3, 0, 0><<<dim3(16, 8), 256, 0, stream>>>(
            nullptr, a2h, a2l, K2, wahh, wahl, 512, qbuf, 512, 512, 512,
            nullptr, nullptr, nullptr, 0, nullptr, nullptr, nullptr, nullptr, 0);
        attn_fused<<<dim3(Bsz), dim3(256), 0, stream>>>(
            att_f, qbuf, wa2, ba2, f_att, a2h, a2l);
        // g2 = A2 @ W2p^T + bih2 + bhh2   (512 x 2048, K=1536; BN=32)
        gemm_sp<64, 32, 64, 2, false, false, 3, 0, 0><<<dim3(64, 8), 256, 0, stream>>>(
            nullptr, a2h, a2l, K2, w2ph, w2pl, K2, gbuf, 2048, 2048, K2,
            bih2, bhh2, nullptr, 0, nullptr, nullptr, nullptr, nullptr, 0);
        lstm_cell_kernel<<<dim3(Bsz * Hh / 256), dim3(256), 0, stream>>>(
            gbuf, c2, a2h, a2l, K2, 1024, nullptr, nullptr, 0, 0);
        // logits GEMM + per-tile argmax epilogue (r7-exact config)
        gemm_sp<64, 64, 64, 2, false, false, 1, 3, 8><<<dim3(NTL, 8), 256, 0, stream>>>(
            nullptr, a2h + 1024, a2l + 1024, K2, woh, wol, 512, nullptr, 0, Vv, 512,
            bo, nullptr, nullptr, 0, nullptr, nullptr, candV, candI, NTL);
        argmax_embed_kernel<<<dim3(Bsz), dim3(256), 0, stream>>>(
            candV, candI, E, a1h, a1l, out, t, NTL);
    }
}

// Round 10
// 3542.266 us; speedup vs baseline: 1.0351x; 1.0351x over previous
//
#include <hip/hip_runtime.h>
#include <math.h>
#include <stdint.h>

// ---- problem dims ----
constexpr int Bsz = 512, Kf = 36, Dd = 2048, Aa = 512, Hh = 512, Em = 300;
constexpr int Vv = 10000, TSTEPS = 19, BOS = 1;
constexpr int K1 = 832;          // padded Em+Hh (812 -> 832)
constexpr int K2 = 1536;         // h1|ctx|h2
constexpr int VvP = 10112;       // vocab rows padded (158 tiles of 64)
constexpr int NTL = VvP / 64;    // 158 logit tiles
constexpr float SPLIT_S  = 2048.0f;
constexpr float SPLIT_IS = 1.0f / 2048.0f;

#define CDIV(a,b) (((a)+(b)-1)/(b))

typedef _Float16 f16x8 __attribute__((ext_vector_type(8)));
typedef float    f32x4 __attribute__((ext_vector_type(4)));

typedef const unsigned int GU __attribute__((address_space(1)));
typedef unsigned int       LU __attribute__((address_space(3)));

__device__ __forceinline__ void gload16(const void* g, void* l) {
    __builtin_amdgcn_global_load_lds((GU*)g, (LU*)l, 16, 0, 0);
}

template<int N> __device__ __forceinline__ void wait_vm() {
    if constexpr (N == 0)       asm volatile("s_waitcnt vmcnt(0)" ::: "memory");
    else if constexpr (N == 4)  asm volatile("s_waitcnt vmcnt(4)" ::: "memory");
    else if constexpr (N == 6)  asm volatile("s_waitcnt vmcnt(6)" ::: "memory");
    else if constexpr (N == 8)  asm volatile("s_waitcnt vmcnt(8)" ::: "memory");
    else if constexpr (N == 12) asm volatile("s_waitcnt vmcnt(12)" ::: "memory");
    else if constexpr (N == 16) asm volatile("s_waitcnt vmcnt(16)" ::: "memory");
    else static_assert(N == 0, "unsupported vmcnt literal");
}
#define WAIT_LGKM asm volatile("s_waitcnt lgkmcnt(0)" ::: "memory")
#define SB0 __builtin_amdgcn_sched_barrier(0)
#define BAR __builtin_amdgcn_s_barrier()

__device__ __forceinline__ float sigm(float v) { return 1.0f / (1.0f + expf(-v)); }

__device__ __forceinline__ void wsplit(_Float16* __restrict__ hi, _Float16* __restrict__ lo,
                                       size_t idx, float v) {
    _Float16 h = (_Float16)v;
    hi[idx] = h;
    lo[idx] = (_Float16)((v - (float)h) * SPLIT_S);
}

// gate-interleave permutation: orig row gate*512+h -> (h/16)*64 + gate*16 + (h%16)
// inverse (col -> orig bias index): ((col&63)>>4)*512 + ((col>>6)<<4) + (col&15)

// ============================================================
// Split-fp16 MFMA GEMM. C[M,N] = A[M,K] @ B[N,K]^T (+bias1+bias2+addC).
// AF32 (DEPTH must be 2): A fp32, reg-prefetch + in-kernel split (K/BK even).
// !AF32: A pre-split, global_load_lds, DEPTH buffers, DEPTH-1 in flight.
// WVM: wave grid rows (2 = 2x2 waves; 4 = 4x1 waves, needed by EPI2).
// PAD: extra halfs per k-plane (0 required if BM or BN == 32).
// SWZ: 1D grid + XCD-bijective swizzle (n fastest, gxn n-tiles); else 2D grid.
// EPI: 0 = store C
//      1 = store C, bias index gate-depermuted
//      2 = LSTM cell epilogue (WVM==4): v = acc + bias(remap) + addC;
//          c update in-place; h split-write to d1 (and d2 if set). No C store.
//      3 = per-tile argmax -> candV/candI (no C store).
// ============================================================
template<int BM, int BN, int BK, int DEPTH, int WVM, bool AF32, bool SWZ, int OCC, int EPI, int PAD>
__global__ __launch_bounds__(256, OCC)
void gemm_sp(const float* __restrict__ Af,
             const _Float16* __restrict__ Ahi, const _Float16* __restrict__ Alo, int lda,
             const _Float16* __restrict__ Bhi, const _Float16* __restrict__ Blo, int ldb,
             float* __restrict__ C, int ldc, int N, int K,
             const float* __restrict__ bias1, const float* __restrict__ bias2,
             const float* __restrict__ addC, int gxn,
             float* __restrict__ cbuf,
             _Float16* __restrict__ d1h, _Float16* __restrict__ d1l, int ld1, int off1,
             _Float16* __restrict__ d2h, _Float16* __restrict__ d2l, int ld2, int off2,
             float* __restrict__ candV, int* __restrict__ candI, int ntl)
{
    static_assert(EPI != 2 || WVM == 4, "LSTM epilogue needs 4x1 wave grid");
    constexpr int WVN = 4 / WVM;
    constexpr int WM = BM / WVM, WN = BN / WVN;
    constexpr int MF = WM / 16, NF = WN / 16;
    constexpr int PA  = BK / 8;
    constexpr int PSA = BM * 8 + PAD;
    constexpr int PSB = BN * 8 + PAD;
    static_assert(PAD == 0 || (BM >= 64 && BN >= 64), "PAD needs wave-aligned planes");
    constexpr int SZA = PA * PSA, SZB = PA * PSB;
    constexpr int OAH = 0, OAL = SZA, OBH = 2 * SZA, OBL = 2 * SZA + SZB;
    constexpr int BUF = 2 * SZA + 2 * SZB;
    constexpr int NCHA = BM * BK / 2048;
    constexpr int NCHB = BN * BK / 2048;
    static_assert(NCHA >= 1 && NCHB >= 1, "tile too small for 256-thread stage");
    constexpr int LW = 2 * NCHA + 2 * NCHB;
    static_assert((DEPTH & (DEPTH - 1)) == 0, "DEPTH pow2");
    static_assert(!AF32 || DEPTH == 2, "AF32 path is double-buffered");
    __shared__ _Float16 sm[DEPTH * BUF];

    int mt, nt;
    if constexpr (SWZ) {
        const int nwg = gridDim.x;
        const int cpx = nwg >> 3;
        const int orig = blockIdx.x;
        const int lid = (orig & 7) * cpx + (orig >> 3);
        nt = lid % gxn; mt = lid / gxn;
    } else {
        nt = blockIdx.x; mt = blockIdx.y;
    }
    const int m0 = mt * BM, n0 = nt * BN;

    const int t    = threadIdx.x;
    const int lane = t & 63;
    const int w    = t >> 6;
    const int wr   = w / WVN, wc = w % WVN;
    const int l15  = lane & 15, l4 = lane >> 4;

    f32x4 acch[MF][NF];
    f32x4 accm[MF][NF];
    #pragma unroll
    for (int m = 0; m < MF; ++m)
        #pragma unroll
        for (int n = 0; n < NF; ++n) {
            acch[m][n] = (f32x4){0.f, 0.f, 0.f, 0.f};
            accm[m][n] = (f32x4){0.f, 0.f, 0.f, 0.f};
        }

    const int nkt = K / BK;

    auto stageB = [&](int bufo, int kt) {
        #pragma unroll
        for (int i = 0; i < NCHB; ++i) {
            const int q  = i * 256 + t;
            const int p  = q / BN, r = q % BN;
            const int qw = i * 256 + (t & ~63);
            const int pu = qw / BN, ru = qw % BN;
            const size_t goff = (size_t)(n0 + r) * ldb + kt * BK + p * 8;
            gload16(Bhi + goff, &sm[bufo + OBH + pu * PSB + ru * 8]);
            gload16(Blo + goff, &sm[bufo + OBL + pu * PSB + ru * 8]);
        }
    };
    auto stageA16 = [&](int bufo, int kt) {
        #pragma unroll
        for (int i = 0; i < NCHA; ++i) {
            const int q  = i * 256 + t;
            const int p  = q / BM, r = q % BM;
            const int qw = i * 256 + (t & ~63);
            const int pu = qw / BM, ru = qw % BM;
            const size_t goff = (size_t)(m0 + r) * lda + kt * BK + p * 8;
            gload16(Ahi + goff, &sm[bufo + OAH + pu * PSA + ru * 8]);
            gload16(Alo + goff, &sm[bufo + OAL + pu * PSA + ru * 8]);
        }
    };
    auto issueA = [&](float4 (&rd)[NCHA][2], int kt) {
        #pragma unroll
        for (int i = 0; i < NCHA; ++i) {
            const int q = i * 256 + t;
            const int p = q / BM, r = q % BM;
            const float* src = Af + (size_t)(m0 + r) * lda + kt * BK + p * 8;
            rd[i][0] = *(const float4*)src;
            rd[i][1] = *(const float4*)(src + 4);
        }
    };
    auto writeA = [&](int bufo, float4 (&rd)[NCHA][2]) {
        #pragma unroll
        for (int i = 0; i < NCHA; ++i) {
            const int q = i * 256 + t;
            const int p = q / BM, r = q % BM;
            const float f[8] = {rd[i][0].x, rd[i][0].y, rd[i][0].z, rd[i][0].w,
                                rd[i][1].x, rd[i][1].y, rd[i][1].z, rd[i][1].w};
            f16x8 hi, lo;
            #pragma unroll
            for (int j = 0; j < 8; ++j) {
                _Float16 h = (_Float16)f[j];
                hi[j] = h;
                lo[j] = (_Float16)((f[j] - (float)h) * SPLIT_S);
            }
            *(f16x8*)&sm[bufo + OAH + p * PSA + r * 8] = hi;
            *(f16x8*)&sm[bufo + OAL + p * PSA + r * 8] = lo;
        }
    };
    auto compute = [&](int bufo) {
        #pragma unroll
        for (int s = 0; s < BK / 32; ++s) {
            f16x8 ah[MF], al[MF], bh[NF], bl[NF];
            const int pl = s * 4 + l4;
            #pragma unroll
            for (int m = 0; m < MF; ++m) {
                const int row = wr * WM + m * 16 + l15;
                ah[m] = *(const f16x8*)&sm[bufo + OAH + pl * PSA + row * 8];
                al[m] = *(const f16x8*)&sm[bufo + OAL + pl * PSA + row * 8];
            }
            #pragma unroll
            for (int n = 0; n < NF; ++n) {
                const int row = wc * WN + n * 16 + l15;
                bh[n] = *(const f16x8*)&sm[bufo + OBH + pl * PSB + row * 8];
                bl[n] = *(const f16x8*)&sm[bufo + OBL + pl * PSB + row * 8];
            }
            #pragma unroll
            for (int m = 0; m < MF; ++m)
                #pragma unroll
                for (int n = 0; n < NF; ++n) {
                    acch[m][n] = __builtin_amdgcn_mfma_f32_16x16x32_f16(ah[m], bh[n], acch[m][n], 0, 0, 0);
                    accm[m][n] = __builtin_amdgcn_mfma_f32_16x16x32_f16(ah[m], bl[n], accm[m][n], 0, 0, 0);
                    accm[m][n] = __builtin_amdgcn_mfma_f32_16x16x32_f16(al[m], bh[n], accm[m][n], 0, 0, 0);
                }
        }
    };

    if constexpr (AF32) {
        float4 rA[NCHA][2], rB[NCHA][2];
        issueA(rA, 0); stageB(0, 0);
        for (int kt = 0; kt < nkt; kt += 2) {
            issueA(rB, kt + 1); stageB(BUF, kt + 1);
            wait_vm<LW>(); SB0;
            writeA(0, rA);
            WAIT_LGKM; SB0;
            BAR; SB0;
            compute(0);
            SB0; WAIT_LGKM; BAR; SB0;
            if (kt + 2 < nkt) { issueA(rA, kt + 2); stageB(0, kt + 2); wait_vm<LW>(); }
            else              { wait_vm<0>(); }
            SB0;
            writeA(BUF, rB);
            WAIT_LGKM; SB0;
            BAR; SB0;
            compute(BUF);
            SB0; WAIT_LGKM; BAR; SB0;
        }
    } else {
        #pragma unroll
        for (int d = 0; d < DEPTH - 1; ++d) { stageA16(d * BUF, d); stageB(d * BUF, d); }
        for (int kt = 0; kt < nkt; ++kt) {
            const int bc = (kt & (DEPTH - 1)) * BUF;
            if (kt + DEPTH - 1 < nkt) {
                const int bn = ((kt + DEPTH - 1) & (DEPTH - 1)) * BUF;
                stageA16(bn, kt + DEPTH - 1); stageB(bn, kt + DEPTH - 1);
                wait_vm<(DEPTH - 1) * LW>();
            } else {
                const int rem = nkt - 1 - kt;
                if constexpr (DEPTH >= 4) {
                    if (rem >= 2)      wait_vm<2 * LW>();
                    else if (rem == 1) wait_vm<LW>();
                    else               wait_vm<0>();
                } else {
                    if (rem >= 1) wait_vm<LW>(); else wait_vm<0>();
                }
            }
            SB0;
            BAR; SB0;
            compute(bc);
            SB0; WAIT_LGKM; BAR; SB0;
        }
    }

    // ---- epilogue ----
    if constexpr (EPI == 0 || EPI == 1) {
        #pragma unroll
        for (int m = 0; m < MF; ++m) {
            const int rowb = m0 + wr * WM + m * 16 + l4 * 4;
            #pragma unroll
            for (int n = 0; n < NF; ++n) {
                const int col = n0 + wc * WN + n * 16 + l15;
                if (col < N) {
                    float bb = 0.f;
                    if (bias1) {
                        int bx = col;
                        if constexpr (EPI == 1)
                            bx = ((col & 63) >> 4) * 512 + ((col >> 6) << 4) + (col & 15);
                        bb += bias1[bx];
                        if (bias2) bb += bias2[bx];
                    }
                    #pragma unroll
                    for (int r = 0; r < 4; ++r) {
                        const size_t idx = (size_t)(rowb + r) * ldc + col;
                        float v = acch[m][n][r] + accm[m][n][r] * SPLIT_IS + bb;
                        if (addC) v += addC[idx];
                        C[idx] = v;
                    }
                }
            }
        }
    } else if constexpr (EPI == 2) {
        // WVM==4: MF==1, NF==4; col n*16+l15 = gate n of h index (n0/4 + l15)
        const int hh = (n0 >> 2) + l15;
        #pragma unroll
        for (int r = 0; r < 4; ++r) {
            const int row = m0 + wr * 16 + l4 * 4 + r;
            float v[4];
            #pragma unroll
            for (int n = 0; n < 4; ++n) {
                const int col = n0 + n * 16 + l15;
                float bb = 0.f;
                if (bias1) {
                    const int bx = ((col & 63) >> 4) * 512 + ((col >> 6) << 4) + (col & 15);
                    bb = bias1[bx] + bias2[bx];
                }
                float x = acch[0][n][r] + accm[0][n][r] * SPLIT_IS + bb;
                if (addC) x += addC[(size_t)row * ldc + col];
                v[n] = x;
            }
            const float cold = cbuf[(size_t)row * Hh + hh];
            const float cv = sigm(v[1]) * cold + sigm(v[0]) * tanhf(v[2]);
            cbuf[(size_t)row * Hh + hh] = cv;
            const float hv = sigm(v[3]) * tanhf(cv);
            wsplit(d1h, d1l, (size_t)row * ld1 + off1 + hh, hv);
            if (d2h) wsplit(d2h, d2l, (size_t)row * ld2 + off2 + hh, hv);
        }
    } else {
        // EPI 3: per-row block-local argmax (global col idx, first-max ties)
        float* sEv = reinterpret_cast<float*>(&sm[0]);
        int*   sEi = reinterpret_cast<int*>(&sm[0]) + 2 * BM;
        float bv[MF][4];
        int   bix[MF][4];
        #pragma unroll
        for (int m = 0; m < MF; ++m)
            #pragma unroll
            for (int r = 0; r < 4; ++r) { bv[m][r] = -INFINITY; bix[m][r] = 0x7fffffff; }
        #pragma unroll
        for (int m = 0; m < MF; ++m)
            #pragma unroll
            for (int r = 0; r < 4; ++r)
                #pragma unroll
                for (int n = 0; n < NF; ++n) {   // n ascending = col ascending
                    const int col = n0 + wc * WN + n * 16 + l15;
                    if (col < N) {
                        const float x = acch[m][n][r] + accm[m][n][r] * SPLIT_IS + bias1[col];
                        if (x > bv[m][r]) { bv[m][r] = x; bix[m][r] = col; }
                    }
                }
        #pragma unroll
        for (int mask = 1; mask < 16; mask <<= 1) {
            #pragma unroll
            for (int m = 0; m < MF; ++m)
                #pragma unroll
                for (int r = 0; r < 4; ++r) {
                    const float ov = __shfl_xor(bv[m][r], mask);
                    const int   oi = __shfl_xor(bix[m][r], mask);
                    if (ov > bv[m][r] || (ov == bv[m][r] && oi < bix[m][r])) {
                        bv[m][r] = ov; bix[m][r] = oi;
                    }
                }
        }
        __syncthreads();
        if (l15 == 0) {
            #pragma unroll
            for (int m = 0; m < MF; ++m)
                #pragma unroll
                for (int r = 0; r < 4; ++r) {
                    const int rl = wr * WM + m * 16 + l4 * 4 + r;
                    sEv[wc * BM + rl] = bv[m][r];
                    sEi[wc * BM + rl] = bix[m][r];
                }
        }
        __syncthreads();
        if (t < BM) {
            float v0 = sEv[t]; int i0 = sEi[t];
            const float v1 = sEv[BM + t]; const int i1 = sEi[BM + t];
            if (v1 > v0 || (v1 == v0 && i1 < i0)) { v0 = v1; i0 = i1; }
            candV[(size_t)(m0 + t) * ntl + nt] = v0;
            candI[(size_t)(m0 + t) * ntl + nt] = i0;
        }
    }
}

// ============================================================
// weight split-convert (optional gate-interleave row permutation)
// ============================================================
__global__ __launch_bounds__(256)
void split_convert(const float* __restrict__ src, int srcld, int validR,
                   _Float16* __restrict__ dhi, _Float16* __restrict__ dlo,
                   int dstld, int coloff, int R, int C, int gperm)
{
    const int total = R * C;
    for (int i = blockIdx.x * 256 + threadIdx.x; i < total; i += gridDim.x * 256) {
        const int r = i / C, c = i % C;
        int dr = r;
        if (gperm) {
            const int gate = r >> 9, h = r & 511;
            dr = ((h >> 4) << 6) + (gate << 4) + (h & 15);
        }
        const float v = (r < validR) ? src[(size_t)r * srcld + c] : 0.f;
        wsplit(dhi, dlo, (size_t)dr * dstld + coloff + c, v);
    }
}

// init: A1[0] = [E[BOS]|0], A1[1] = 0, A2[0] = A2[1] = 0, c1 = c2 = 0
__global__ __launch_bounds__(256)
void init_kernel(_Float16* __restrict__ a1h0, _Float16* __restrict__ a1l0,
                 _Float16* __restrict__ a1h1, _Float16* __restrict__ a1l1,
                 _Float16* __restrict__ a2h0, _Float16* __restrict__ a2l0,
                 _Float16* __restrict__ a2h1, _Float16* __restrict__ a2l1,
                 float* __restrict__ c1, float* __restrict__ c2,
                 const float* __restrict__ E)
{
    const int idx = blockIdx.x * 256 + threadIdx.x;   // grid covers 512*1536
    if (idx < Bsz * K1) {
        const int col = idx % K1;
        const float v = (col < Em) ? E[(size_t)BOS * Em + col] : 0.f;
        wsplit(a1h0, a1l0, idx, v);
        wsplit(a1h1, a1l1, idx, 0.f);
    }
    if (idx < Bsz * K2) {
        wsplit(a2h0, a2l0, idx, 0.f);
        wsplit(a2h1, a2l1, idx, 0.f);
    }
    if (idx < Bsz * Hh) { c1[idx] = 0.f; c2[idx] = 0.f; }
}

// f_mean (fp32 + split pair)
__global__ __launch_bounds__(256)
void fmean_kernel(const float* __restrict__ f_att, float* __restrict__ f_mean,
                  _Float16* __restrict__ fmh, _Float16* __restrict__ fml)
{
    const int b = blockIdx.x;
    for (int a = threadIdx.x; a < Aa; a += 256) {
        float s = 0.f;
        for (int k = 0; k < Kf; ++k) s += f_att[((size_t)b * Kf + k) * Aa + a];
        const float v = s * (1.0f / 36.0f);
        f_mean[(size_t)b * Aa + a] = v;
        wsplit(fmh, fml, (size_t)b * Aa + a, v);
    }
}

// Fused attention: e scores (tanh dot with GEMM-produced q), softmax over k,
// ctx -> A2 cols [512,1024). One block per b.
__global__ __launch_bounds__(256)
void attn_fused(const float* __restrict__ att_f, const float* __restrict__ q,
                const float* __restrict__ wa2, const float* __restrict__ ba2,
                const float* __restrict__ f_att,
                _Float16* __restrict__ a2h, _Float16* __restrict__ a2l)
{
    const int b = blockIdx.x, tid = threadIdx.x;
    const int w = tid >> 6, lane = tid & 63;
    __shared__ float se[Kf];
    __shared__ float wk[Kf];
    const float* pq = q + (size_t)b * Aa;
    for (int k = w; k < Kf; k += 4) {
        const float* pf = att_f + ((size_t)b * Kf + k) * Aa;
        float s = 0.f;
        #pragma unroll
        for (int j = 0; j < Aa; j += 64) {
            const int a = j + lane;
            s += tanhf(pf[a] + pq[a]) * wa2[a];
        }
        #pragma unroll
        for (int off = 32; off; off >>= 1) s += __shfl_down(s, off);
        if (lane == 0) se[k] = s + ba2[0];
    }
    __syncthreads();
    if (tid < Kf) {
        float mx = -INFINITY;
        for (int k = 0; k < Kf; ++k) mx = fmaxf(mx, se[k]);
        float ssum = 0.f;
        for (int k = 0; k < Kf; ++k) ssum += expf(se[k] - mx);
        wk[tid] = expf(se[tid] - mx) / ssum;
    }
    __syncthreads();
    for (int a = tid; a < Aa; a += 256) {
        float acc = 0.f;
        for (int k = 0; k < Kf; ++k)
            acc = fmaf(wk[k], f_att[((size_t)b * Kf + k) * Aa + a], acc);
        wsplit(a2h, a2l, (size_t)b * K2 + Hh + a, acc);
    }
}

// final argmax over per-tile candidates + embed gather -> A1_nxt cols [0,300)
__global__ __launch_bounds__(256)
void argmax_embed_kernel(const float* __restrict__ candV, const int* __restrict__ candI,
                         const float* __restrict__ E,
                         _Float16* __restrict__ a1h, _Float16* __restrict__ a1l,
                         int* __restrict__ out, int t, int ntl)
{
    const int b = blockIdx.x;
    const int tid = threadIdx.x;
    __shared__ float sv[256];
    __shared__ int   si[256];
    float bvv = -INFINITY; int bii = 0x7fffffff;
    if (tid < ntl) { bvv = candV[(size_t)b * ntl + tid]; bii = candI[(size_t)b * ntl + tid]; }
    sv[tid] = bvv; si[tid] = bii;
    __syncthreads();
    for (int s = 128; s > 0; s >>= 1) {
        if (tid < s) {
            const float v2 = sv[tid + s];
            const int   i2 = si[tid + s];
            if (v2 > sv[tid] || (v2 == sv[tid] && i2 < si[tid])) { sv[tid] = v2; si[tid] = i2; }
        }
        __syncthreads();
    }
    const int idx = si[0];
    if (tid == 0) out[(size_t)b * TSTEPS + t] = idx;
    for (int d = tid; d < Em; d += 256)
        wsplit(a1h, a1l, (size_t)b * K1 + d, E[(size_t)idx * Em + d]);
}

// ============================================================
// host side
// ============================================================
static inline void conv(hipStream_t s, const float* src, int srcld, int validR,
                        _Float16* dhi, _Float16* dlo, int dstld, int coloff,
                        int R, int C, int gperm)
{
    int blocks = CDIV(R * C, 256); if (blocks > 2048) blocks = 2048;
    split_convert<<<dim3(blocks), dim3(256), 0, s>>>(src, srcld, validR, dhi, dlo,
                                                     dstld, coloff, R, C, gperm);
}

extern "C" void kernel_launch(void* const* d_in, const int* in_sizes, int n_in,
                              void* d_out, int out_size, void* d_ws, size_t ws_size,
                              hipStream_t stream)
{
    const float* feats = (const float*)d_in[0];
    const float* Wp    = (const float*)d_in[1];
    const float* bp    = (const float*)d_in[2];
    const float* E     = (const float*)d_in[3];
    const float* Wih1  = (const float*)d_in[4];
    const float* Whh1  = (const float*)d_in[5];
    const float* bih1  = (const float*)d_in[6];
    const float* bhh1  = (const float*)d_in[7];
    const float* Wih2  = (const float*)d_in[8];
    const float* Whh2  = (const float*)d_in[9];
    const float* bih2  = (const float*)d_in[10];
    const float* bhh2  = (const float*)d_in[11];
    const float* Wa1   = (const float*)d_in[12];
    const float* ba1   = (const float*)d_in[13];
    const float* wa2   = (const float*)d_in[14];
    const float* ba2   = (const float*)d_in[15];
    const float* Wo    = (const float*)d_in[16];
    const float* bo    = (const float*)d_in[17];
    int* out = (int*)d_out;
    (void)in_sizes; (void)n_in; (void)out_size; (void)ws_size;

    uint8_t* w = (uint8_t*)d_ws;
    size_t off = 0;
    auto alloc = [&](size_t bytes) { void* p = w + off; off = (off + bytes + 255) & ~(size_t)255; return p; };

    float*     f_att  = (float*)alloc(18432ull * 512 * 4);
    float*     att_f  = (float*)alloc(18432ull * 512 * 4);
    float*     f_mean = (float*)alloc(512ull * 512 * 4);
    _Float16*  fmh    = (_Float16*)alloc(512ull * 512 * 2);
    _Float16*  fml    = (_Float16*)alloc(512ull * 512 * 2);
    _Float16*  wph    = (_Float16*)alloc(512ull * 2048 * 2);
    _Float16*  wpl    = (_Float16*)alloc(512ull * 2048 * 2);
    _Float16*  w1ph   = (_Float16*)alloc(2048ull * K1 * 2);
    _Float16*  w1pl   = (_Float16*)alloc(2048ull * K1 * 2);
    _Float16*  w1ch   = (_Float16*)alloc(2048ull * 512 * 2);
    _Float16*  w1cl   = (_Float16*)alloc(2048ull * 512 * 2);
    _Float16*  w2ph   = (_Float16*)alloc(2048ull * K2 * 2);
    _Float16*  w2pl   = (_Float16*)alloc(2048ull * K2 * 2);
    _Float16*  wahh   = (_Float16*)alloc(512ull * 512 * 2);
    _Float16*  wahl   = (_Float16*)alloc(512ull * 512 * 2);
    _Float16*  wafh   = (_Float16*)alloc(512ull * 512 * 2);
    _Float16*  wafl   = (_Float16*)alloc(512ull * 512 * 2);
    _Float16*  woh    = (_Float16*)alloc((size_t)VvP * 512 * 2);
    _Float16*  wol    = (_Float16*)alloc((size_t)VvP * 512 * 2);
    float*     g1c    = (float*)alloc(512ull * 2048 * 4);
    _Float16*  a1h[2] = {(_Float16*)alloc(512ull * K1 * 2), (_Float16*)alloc(512ull * K1 * 2)};
    _Float16*  a1l[2] = {(_Float16*)alloc(512ull * K1 * 2), (_Float16*)alloc(512ull * K1 * 2)};
    _Float16*  a2h[2] = {(_Float16*)alloc(512ull * K2 * 2), (_Float16*)alloc(512ull * K2 * 2)};
    _Float16*  a2l[2] = {(_Float16*)alloc(512ull * K2 * 2), (_Float16*)alloc(512ull * K2 * 2)};
    float*     c1     = (float*)alloc(512ull * 512 * 4);
    float*     c2     = (float*)alloc(512ull * 512 * 4);
    float*     qbuf   = (float*)alloc(512ull * 512 * 4);
    float*     candV  = (float*)alloc(512ull * NTL * 4);
    int*       candI  = (int*)alloc(512ull * NTL * 4);

    // ---- weight conversions (g1/g2 weights gate-interleaved) ----
    conv(stream, Wp,        Dd,      512,  wph,  wpl,  2048, 0,    512,  2048, 0);
    conv(stream, Wih1,      Em + Aa, 2048, w1ph, w1pl, K1,   0,    2048, Em,   1);
    conv(stream, Whh1,      Hh,      2048, w1ph, w1pl, K1,   Em,   2048, 512,  1);
    conv(stream, Wih1,      Em + Aa, 0,    w1ph, w1pl, K1,   812,  2048, 20,   0);  // zero pad
    conv(stream, Wih1 + Em, Em + Aa, 2048, w1ch, w1cl, 512,  0,    2048, 512,  1);
    conv(stream, Wih2,      Hh + Aa, 2048, w2ph, w2pl, K2,   0,    2048, 1024, 1);
    conv(stream, Whh2,      Hh,      2048, w2ph, w2pl, K2,   1024, 2048, 512,  1);
    conv(stream, Wa1,       Hh + Aa, 512,  wahh, wahl, 512,  0,    512,  512,  0);
    conv(stream, Wa1 + Hh,  Hh + Aa, 512,  wafh, wafl, 512,  0,    512,  512,  0);
    conv(stream, Wo,        Hh,      Vv,   woh,  wol,  512,  0,    VvP,  512,  0);

    init_kernel<<<dim3(CDIV(Bsz * K2, 256)), dim3(256), 0, stream>>>(
        a1h[0], a1l[0], a1h[1], a1l[1], a2h[0], a2l[0], a2h[1], a2l[1], c1, c2, E);

    // ---- precompute (r7-exact configs) ----
    // f_att = feats @ Wp^T + bp   (M=18432 N=512 K=2048; swizzled, NFAST)
    gemm_sp<128, 64, 32, 2, 2, true, true, 2, 0, 8><<<dim3(1152), 256, 0, stream>>>(
        feats, nullptr, nullptr, Dd, wph, wpl, 2048, f_att, 512, 512, 2048,
        bp, nullptr, nullptr, 8,
        nullptr, nullptr, nullptr, 0, 0, nullptr, nullptr, 0, 0, nullptr, nullptr, 0);
    fmean_kernel<<<dim3(Bsz), dim3(256), 0, stream>>>(f_att, f_mean, fmh, fml);
    // g1c = f_mean @ W1c^T + bih1 + bhh1  (permuted cols, EPI1 bias remap)
    gemm_sp<64, 64, 64, 2, 2, false, false, 1, 1, 8><<<dim3(32, 8), 256, 0, stream>>>(
        nullptr, fmh, fml, 512, w1ch, w1cl, 512, g1c, 2048, 2048, 512,
        bih1, bhh1, nullptr, 0,
        nullptr, nullptr, nullptr, 0, 0, nullptr, nullptr, 0, 0, nullptr, nullptr, 0);
    // att_f = f_att @ Wa1[:,H:]^T + ba1   (18432 x 512, K=512; swizzled)
    gemm_sp<128, 64, 32, 2, 2, true, true, 2, 0, 8><<<dim3(1152), 256, 0, stream>>>(
        f_att, nullptr, nullptr, 512, wafh, wafl, 512, att_f, 512, 512, 512,
        ba1, nullptr, nullptr, 8,
        nullptr, nullptr, nullptr, 0, 0, nullptr, nullptr, 0, 0, nullptr, nullptr, 0);

    // ---- decode loop (6 launches/step; ping-pong A1/A2) ----
    for (int t = 0; t < TSTEPS; ++t) {
        const int cur = t & 1, nxt = cur ^ 1;
        // g1 GEMM + LSTM1 epilogue: reads A1[cur]; h1 -> A2[cur][0,512) and
        // A1[nxt][300,812); c1 in-place. addC = g1c (permuted, biases included).
        gemm_sp<64, 64, 32, 2, 4, false, false, 3, 2, 8><<<dim3(32, 8), 256, 0, stream>>>(
            nullptr, a1h[cur], a1l[cur], K1, w1ph, w1pl, K1, nullptr, 2048, 2048, K1,
            nullptr, nullptr, g1c, 0,
            c1, a2h[cur], a2l[cur], K2, 0, a1h[nxt], a1l[nxt], K1, Em,
            nullptr, nullptr, 0);
        // q = h1 @ Wa1[:,:H]^T   (512 x 512, K=512)
        gemm_sp<64, 64, 64, 2, 2, false, false, 1, 0, 8><<<dim3(8, 8), 256, 0, stream>>>(
            nullptr, a2h[cur], a2l[cur], K2, wahh, wahl, 512, qbuf, 512, 512, 512,
            nullptr, nullptr, nullptr, 0,
            nullptr, nullptr, nullptr, 0, 0, nullptr, nullptr, 0, 0, nullptr, nullptr, 0);
        attn_fused<<<dim3(Bsz), dim3(256), 0, stream>>>(
            att_f, qbuf, wa2, ba2, f_att, a2h[cur], a2l[cur]);
        // g2 GEMM + LSTM2 epilogue: reads A2[cur]; h2 -> A2[nxt][1024,1536); c2 in-place
        gemm_sp<64, 64, 32, 2, 4, false, false, 3, 2, 8><<<dim3(32, 8), 256, 0, stream>>>(
            nullptr, a2h[cur], a2l[cur], K2, w2ph, w2pl, K2, nullptr, 2048, 2048, K2,
            bih2, bhh2, nullptr, 0,
            c2, a2h[nxt], a2l[nxt], K2, 1024, nullptr, nullptr, 0, 0,
            nullptr, nullptr, 0);
        // logits GEMM + per-tile argmax epilogue (h2 = A2[nxt] cols [1024,1536))
        gemm_sp<64, 64, 64, 2, 2, false, false, 1, 3, 8><<<dim3(NTL, 8), 256, 0, stream>>>(
            nullptr, a2h[nxt] + 1024, a2l[nxt] + 1024, K2, woh, wol, 512, nullptr, 0, Vv, 512,
            bo, nullptr, nullptr, 0,
            nullptr, nullptr, nullptr, 0, 0, nullptr, nullptr, 0, 0, candV, candI, NTL);
        argmax_embed_kernel<<<dim3(Bsz), dim3(256), 0, stream>>>(
            candV, candI, E, a1h[nxt], a1l[nxt], out, t, NTL);
    }
}

// Round 12
// 3383.516 us; speedup vs baseline: 1.0837x; 1.0469x over previous
//
#include <hip/hip_runtime.h>
#include <math.h>
#include <stdint.h>

// ---- problem dims ----
constexpr int Bsz = 512, Kf = 36, Dd = 2048, Aa = 512, Hh = 512, Em = 300;
constexpr int Vv = 10000, TSTEPS = 19, BOS = 1;
constexpr int K1 = 832;          // padded Em+Hh (812 -> 832)
constexpr int K2 = 1536;         // h1|ctx|h2
constexpr int VvP = 10112;       // vocab rows padded (158 tiles of 64)
constexpr int NTL = VvP / 64;    // 158 logit tiles
constexpr float SPLIT_S  = 2048.0f;
constexpr float SPLIT_IS = 1.0f / 2048.0f;

#define CDIV(a,b) (((a)+(b)-1)/(b))

typedef _Float16 f16x8 __attribute__((ext_vector_type(8)));
typedef float    f32x4 __attribute__((ext_vector_type(4)));

typedef const unsigned int GU __attribute__((address_space(1)));
typedef unsigned int       LU __attribute__((address_space(3)));

__device__ __forceinline__ void gload16(const void* g, void* l) {
    __builtin_amdgcn_global_load_lds((GU*)g, (LU*)l, 16, 0, 0);
}

template<int N> __device__ __forceinline__ void wait_vm() {
    if constexpr (N == 0)       asm volatile("s_waitcnt vmcnt(0)" ::: "memory");
    else if constexpr (N == 3)  asm volatile("s_waitcnt vmcnt(3)" ::: "memory");
    else if constexpr (N == 6)  asm volatile("s_waitcnt vmcnt(6)" ::: "memory");
    else if constexpr (N == 8)  asm volatile("s_waitcnt vmcnt(8)" ::: "memory");
    else static_assert(N == 0, "unsupported vmcnt literal");
}
#define WAIT_LGKM asm volatile("s_waitcnt lgkmcnt(0)" ::: "memory")
#define SB0 __builtin_amdgcn_sched_barrier(0)
#define BAR __builtin_amdgcn_s_barrier()

__device__ __forceinline__ float sigm(float v) { return 1.0f / (1.0f + expf(-v)); }

__device__ __forceinline__ void wsplit(_Float16* __restrict__ hi, _Float16* __restrict__ lo,
                                       size_t idx, float v) {
    _Float16 h = (_Float16)v;
    hi[idx] = h;
    lo[idx] = (_Float16)((v - (float)h) * SPLIT_S);
}

// gate-interleave permutation: orig row gate*512+h -> (h/16)*64 + gate*16 + (h%16)
// inverse (col -> orig bias index): ((col&63)>>4)*512 + ((col>>6)<<4) + (col&15)

// ============================================================
// Split-fp16 MFMA GEMM (pre-split A, global_load_lds, DEPTH=2).
// WVM: wave grid rows (2 = 2x2 waves; 4 = 4x1 waves, needed by EPI2).
// EPI: 0 = store C (+bias1+bias2+addC)
//      1 = store C, bias index gate-depermuted
//      2 = LSTM cell epilogue (WVM==4): v = acc + bias(remap) + addC;
//          c update in-place; h split-write to d1 (and d2 if set). No C store.
//      3 = per-tile argmax -> candV/candI (no C store).
// ============================================================
template<int BM, int BN, int BK, int WVM, int OCC, int EPI>
__global__ __launch_bounds__(256, OCC)
void gemm_sp(const _Float16* __restrict__ Ahi, const _Float16* __restrict__ Alo, int lda,
             const _Float16* __restrict__ Bhi, const _Float16* __restrict__ Blo, int ldb,
             float* __restrict__ C, int ldc, int N, int K,
             const float* __restrict__ bias1, const float* __restrict__ bias2,
             const float* __restrict__ addC,
             float* __restrict__ cbuf,
             _Float16* __restrict__ d1h, _Float16* __restrict__ d1l, int ld1, int off1,
             _Float16* __restrict__ d2h, _Float16* __restrict__ d2l, int ld2, int off2,
             float* __restrict__ candV, int* __restrict__ candI, int ntl)
{
    static_assert(EPI != 2 || WVM == 4, "LSTM epilogue needs 4x1 wave grid");
    constexpr int WVN = 4 / WVM;
    constexpr int WM = BM / WVM, WN = BN / WVN;
    constexpr int MF = WM / 16, NF = WN / 16;
    constexpr int PA  = BK / 8;
    constexpr int PSA = BM * 8 + 8;
    constexpr int PSB = BN * 8 + 8;
    constexpr int SZA = PA * PSA, SZB = PA * PSB;
    constexpr int OAH = 0, OAL = SZA, OBH = 2 * SZA, OBL = 2 * SZA + SZB;
    constexpr int BUF = 2 * SZA + 2 * SZB;
    constexpr int NCHA = BM * BK / 2048;
    constexpr int NCHB = BN * BK / 2048;
    constexpr int LW = 2 * NCHA + 2 * NCHB;
    __shared__ _Float16 sm[2 * BUF];

    const int nt = blockIdx.x, mt = blockIdx.y;
    const int m0 = mt * BM, n0 = nt * BN;

    const int t    = threadIdx.x;
    const int lane = t & 63;
    const int w    = t >> 6;
    const int wr   = w / WVN, wc = w % WVN;
    const int l15  = lane & 15, l4 = lane >> 4;

    f32x4 acch[MF][NF];
    f32x4 accm[MF][NF];
    #pragma unroll
    for (int m = 0; m < MF; ++m)
        #pragma unroll
        for (int n = 0; n < NF; ++n) {
            acch[m][n] = (f32x4){0.f, 0.f, 0.f, 0.f};
            accm[m][n] = (f32x4){0.f, 0.f, 0.f, 0.f};
        }

    const int nkt = K / BK;

    auto stage = [&](int bufo, int kt) {
        #pragma unroll
        for (int i = 0; i < NCHA; ++i) {
            const int q  = i * 256 + t;
            const int p  = q / BM, r = q % BM;
            const int qw = i * 256 + (t & ~63);
            const int pu = qw / BM, ru = qw % BM;
            const size_t goff = (size_t)(m0 + r) * lda + kt * BK + p * 8;
            gload16(Ahi + goff, &sm[bufo + OAH + pu * PSA + ru * 8]);
            gload16(Alo + goff, &sm[bufo + OAL + pu * PSA + ru * 8]);
        }
        #pragma unroll
        for (int i = 0; i < NCHB; ++i) {
            const int q  = i * 256 + t;
            const int p  = q / BN, r = q % BN;
            const int qw = i * 256 + (t & ~63);
            const int pu = qw / BN, ru = qw % BN;
            const size_t goff = (size_t)(n0 + r) * ldb + kt * BK + p * 8;
            gload16(Bhi + goff, &sm[bufo + OBH + pu * PSB + ru * 8]);
            gload16(Blo + goff, &sm[bufo + OBL + pu * PSB + ru * 8]);
        }
    };
    auto compute = [&](int bufo) {
        #pragma unroll
        for (int s = 0; s < BK / 32; ++s) {
            f16x8 ah[MF], al[MF], bh[NF], bl[NF];
            const int pl = s * 4 + l4;
            #pragma unroll
            for (int m = 0; m < MF; ++m) {
                const int row = wr * WM + m * 16 + l15;
                ah[m] = *(const f16x8*)&sm[bufo + OAH + pl * PSA + row * 8];
                al[m] = *(const f16x8*)&sm[bufo + OAL + pl * PSA + row * 8];
            }
            #pragma unroll
            for (int n = 0; n < NF; ++n) {
                const int row = wc * WN + n * 16 + l15;
                bh[n] = *(const f16x8*)&sm[bufo + OBH + pl * PSB + row * 8];
                bl[n] = *(const f16x8*)&sm[bufo + OBL + pl * PSB + row * 8];
            }
            #pragma unroll
            for (int m = 0; m < MF; ++m)
                #pragma unroll
                for (int n = 0; n < NF; ++n) {
                    acch[m][n] = __builtin_amdgcn_mfma_f32_16x16x32_f16(ah[m], bh[n], acch[m][n], 0, 0, 0);
                    accm[m][n] = __builtin_amdgcn_mfma_f32_16x16x32_f16(ah[m], bl[n], accm[m][n], 0, 0, 0);
                    accm[m][n] = __builtin_amdgcn_mfma_f32_16x16x32_f16(al[m], bh[n], accm[m][n], 0, 0, 0);
                }
        }
    };

    stage(0, 0);
    for (int kt = 0; kt < nkt; ++kt) {
        const int bc = (kt & 1) * BUF;
        if (kt + 1 < nkt) { stage(BUF - bc, kt + 1); wait_vm<LW>(); }
        else              { wait_vm<0>(); }
        SB0;
        BAR; SB0;
        compute(bc);
        SB0; WAIT_LGKM; BAR; SB0;
    }

    // ---- epilogue ----
    if constexpr (EPI == 0 || EPI == 1) {
        #pragma unroll
        for (int m = 0; m < MF; ++m) {
            const int rowb = m0 + wr * WM + m * 16 + l4 * 4;
            #pragma unroll
            for (int n = 0; n < NF; ++n) {
                const int col = n0 + wc * WN + n * 16 + l15;
                if (col < N) {
                    float bb = 0.f;
                    if (bias1) {
                        int bx = col;
                        if constexpr (EPI == 1)
                            bx = ((col & 63) >> 4) * 512 + ((col >> 6) << 4) + (col & 15);
                        bb += bias1[bx];
                        if (bias2) bb += bias2[bx];
                    }
                    #pragma unroll
                    for (int r = 0; r < 4; ++r) {
                        const size_t idx = (size_t)(rowb + r) * ldc + col;
                        float v = acch[m][n][r] + accm[m][n][r] * SPLIT_IS + bb;
                        if (addC) v += addC[idx];
                        C[idx] = v;
                    }
                }
            }
        }
    } else if constexpr (EPI == 2) {
        // WVM==4: MF==1, NF==4; col n*16+l15 = gate n of h index (n0/4 + l15)
        const int hh = (n0 >> 2) + l15;
        #pragma unroll
        for (int r = 0; r < 4; ++r) {
            const int row = m0 + wr * 16 + l4 * 4 + r;
            float v[4];
            #pragma unroll
            for (int n = 0; n < 4; ++n) {
                const int col = n0 + n * 16 + l15;
                float bb = 0.f;
                if (bias1) {
                    const int bx = ((col & 63) >> 4) * 512 + ((col >> 6) << 4) + (col & 15);
                    bb = bias1[bx] + bias2[bx];
                }
                float x = acch[0][n][r] + accm[0][n][r] * SPLIT_IS + bb;
                if (addC) x += addC[(size_t)row * ldc + col];
                v[n] = x;
            }
            const float cold = cbuf[(size_t)row * Hh + hh];
            const float cv = sigm(v[1]) * cold + sigm(v[0]) * tanhf(v[2]);
            cbuf[(size_t)row * Hh + hh] = cv;
            const float hv = sigm(v[3]) * tanhf(cv);
            wsplit(d1h, d1l, (size_t)row * ld1 + off1 + hh, hv);
            if (d2h) wsplit(d2h, d2l, (size_t)row * ld2 + off2 + hh, hv);
        }
    } else {
        // EPI 3: per-row block-local argmax (global col idx, first-max ties)
        float* sEv = reinterpret_cast<float*>(&sm[0]);
        int*   sEi = reinterpret_cast<int*>(&sm[0]) + 2 * BM;
        float bv[MF][4];
        int   bix[MF][4];
        #pragma unroll
        for (int m = 0; m < MF; ++m)
            #pragma unroll
            for (int r = 0; r < 4; ++r) { bv[m][r] = -INFINITY; bix[m][r] = 0x7fffffff; }
        #pragma unroll
        for (int m = 0; m < MF; ++m)
            #pragma unroll
            for (int r = 0; r < 4; ++r)
                #pragma unroll
                for (int n = 0; n < NF; ++n) {   // n ascending = col ascending
                    const int col = n0 + wc * WN + n * 16 + l15;
                    if (col < N) {
                        const float x = acch[m][n][r] + accm[m][n][r] * SPLIT_IS + bias1[col];
                        if (x > bv[m][r]) { bv[m][r] = x; bix[m][r] = col; }
                    }
                }
        #pragma unroll
        for (int mask = 1; mask < 16; mask <<= 1) {
            #pragma unroll
            for (int m = 0; m < MF; ++m)
                #pragma unroll
                for (int r = 0; r < 4; ++r) {
                    const float ov = __shfl_xor(bv[m][r], mask);
                    const int   oi = __shfl_xor(bix[m][r], mask);
                    if (ov > bv[m][r] || (ov == bv[m][r] && oi < bix[m][r])) {
                        bv[m][r] = ov; bix[m][r] = oi;
                    }
                }
        }
        __syncthreads();
        if (l15 == 0) {
            #pragma unroll
            for (int m = 0; m < MF; ++m)
                #pragma unroll
                for (int r = 0; r < 4; ++r) {
                    const int rl = wr * WM + m * 16 + l4 * 4 + r;
                    sEv[wc * BM + rl] = bv[m][r];
                    sEi[wc * BM + rl] = bix[m][r];
                }
        }
        __syncthreads();
        if (t < BM) {
            float v0 = sEv[t]; int i0 = sEi[t];
            const float v1 = sEv[BM + t]; const int i1 = sEi[BM + t];
            if (v1 > v0 || (v1 == v0 && i1 < i0)) { v0 = v1; i0 = i1; }
            candV[(size_t)(m0 + t) * ntl + nt] = v0;
            candI[(size_t)(m0 + t) * ntl + nt] = i0;
        }
    }
}

// ============================================================
// 512-thread AF32 big GEMM: 128x64 tile, BK=32, 8 waves (4x2 grid).
// A fp32 reg-prefetch + in-kernel split; per-element K-chain identical
// to the 256-thread version (bit-identical outputs). XCD swizzle.
// ============================================================
__global__ __launch_bounds__(512, 4)
void gemm_af32(const float* __restrict__ Af, int lda,
               const _Float16* __restrict__ Bhi, const _Float16* __restrict__ Blo, int ldb,
               float* __restrict__ C, int ldc, int N, int K,
               const float* __restrict__ bias1, int gxn)
{
    constexpr int BM = 128, BN = 64, BK = 32;
    constexpr int WM = 32, WN = 32;            // 4x2 wave grid
    constexpr int MF = 2, NF = 2;
    constexpr int PSA = BM * 8 + 8;            // 1032
    constexpr int PSB = BN * 8 + 8;            // 520
    constexpr int PA  = BK / 8;                // 4
    constexpr int SZA = PA * PSA, SZB = PA * PSB;
    constexpr int OAH = 0, OAL = SZA, OBH = 2 * SZA, OBL = 2 * SZA + SZB;
    constexpr int BUF = 2 * SZA + 2 * SZB;
    __shared__ _Float16 sm[2 * BUF];           // 49664 B

    const int nwg = gridDim.x;
    const int cpx = nwg >> 3;
    const int orig = blockIdx.x;
    const int lid = (orig & 7) * cpx + (orig >> 3);
    const int nt = lid % gxn, mt = lid / gxn;
    const int m0 = mt * BM, n0 = nt * BN;

    const int t    = threadIdx.x;              // 0..511
    const int lane = t & 63;
    const int w    = t >> 6;                   // 0..7
    const int wr   = w >> 1, wc = w & 1;       // 4x2
    const int l15  = lane & 15, l4 = lane >> 4;
    const int ar   = t >> 2, ac = t & 3;       // A chunk: row, k-plane

    f32x4 acch[MF][NF];
    f32x4 accm[MF][NF];
    #pragma unroll
    for (int m = 0; m < MF; ++m)
        #pragma unroll
        for (int n = 0; n < NF; ++n) {
            acch[m][n] = (f32x4){0.f, 0.f, 0.f, 0.f};
            accm[m][n] = (f32x4){0.f, 0.f, 0.f, 0.f};
        }

    const int nkt = K / BK;   // even at both call sites (64, 16)

    auto issueA = [&](float4 (&rd)[2], int kt) {
        const float* src = Af + (size_t)(m0 + ar) * lda + kt * BK + ac * 8;
        rd[0] = *(const float4*)src;
        rd[1] = *(const float4*)(src + 4);
    };
    auto writeA = [&](int bufo, float4 (&rd)[2]) {
        const float f[8] = {rd[0].x, rd[0].y, rd[0].z, rd[0].w,
                            rd[1].x, rd[1].y, rd[1].z, rd[1].w};
        f16x8 hi, lo;
        #pragma unroll
        for (int j = 0; j < 8; ++j) {
            _Float16 h = (_Float16)f[j];
            hi[j] = h;
            lo[j] = (_Float16)((f[j] - (float)h) * SPLIT_S);
        }
        *(f16x8*)&sm[bufo + OAH + ac * PSA + ar * 8] = hi;
        *(f16x8*)&sm[bufo + OAL + ac * PSA + ar * 8] = lo;
    };
    // B: 256 hi-chunks (waves 0-3) + 256 lo-chunks (waves 4-7); 1 gload16/thread
    auto stageB = [&](int bufo, int kt) {
        const int q = t & 255;
        const int p = q >> 6, r = q & 63;
        const _Float16* src = (t < 256) ? Bhi : Blo;
        const int base = (t < 256) ? (bufo + OBH) : (bufo + OBL);
        const size_t goff = (size_t)(n0 + r) * ldb + kt * BK + p * 8;
        gload16(src + goff, &sm[base + p * PSB + r * 8]);
    };
    auto compute = [&](int bufo) {
        f16x8 ah[MF], al[MF], bh[NF], bl[NF];
        const int pl = l4;
        #pragma unroll
        for (int m = 0; m < MF; ++m) {
            const int row = wr * WM + m * 16 + l15;
            ah[m] = *(const f16x8*)&sm[bufo + OAH + pl * PSA + row * 8];
            al[m] = *(const f16x8*)&sm[bufo + OAL + pl * PSA + row * 8];
        }
        #pragma unroll
        for (int n = 0; n < NF; ++n) {
            const int row = wc * WN + n * 16 + l15;
            bh[n] = *(const f16x8*)&sm[bufo + OBH + pl * PSB + row * 8];
            bl[n] = *(const f16x8*)&sm[bufo + OBL + pl * PSB + row * 8];
        }
        #pragma unroll
        for (int m = 0; m < MF; ++m)
            #pragma unroll
            for (int n = 0; n < NF; ++n) {
                acch[m][n] = __builtin_amdgcn_mfma_f32_16x16x32_f16(ah[m], bh[n], acch[m][n], 0, 0, 0);
                accm[m][n] = __builtin_amdgcn_mfma_f32_16x16x32_f16(ah[m], bl[n], accm[m][n], 0, 0, 0);
                accm[m][n] = __builtin_amdgcn_mfma_f32_16x16x32_f16(al[m], bh[n], accm[m][n], 0, 0, 0);
            }
    };

    float4 rA[2], rB[2];
    issueA(rA, 0); stageB(0, 0);               // 3 outstanding per thread
    for (int kt = 0; kt < nkt; kt += 2) {
        issueA(rB, kt + 1); stageB(BUF, kt + 1);
        wait_vm<3>(); SB0;                      // rA + B(kt) complete
        writeA(0, rA);
        WAIT_LGKM; SB0;
        BAR; SB0;
        compute(0);
        SB0; WAIT_LGKM; BAR; SB0;
        if (kt + 2 < nkt) { issueA(rA, kt + 2); stageB(0, kt + 2); wait_vm<3>(); }
        else              { wait_vm<0>(); }
        SB0;
        writeA(BUF, rB);
        WAIT_LGKM; SB0;
        BAR; SB0;
        compute(BUF);
        SB0; WAIT_LGKM; BAR; SB0;
    }

    #pragma unroll
    for (int m = 0; m < MF; ++m) {
        const int rowb = m0 + wr * WM + m * 16 + l4 * 4;
        #pragma unroll
        for (int n = 0; n < NF; ++n) {
            const int col = n0 + wc * WN + n * 16 + l15;
            float bb = bias1 ? bias1[col] : 0.f;
            #pragma unroll
            for (int r = 0; r < 4; ++r) {
                const size_t idx = (size_t)(rowb + r) * ldc + col;
                C[idx] = acch[m][n][r] + accm[m][n][r] * SPLIT_IS + bb;
            }
        }
    }
}

// ============================================================
// weight split-convert (optional gate-interleave row permutation)
// ============================================================
__global__ __launch_bounds__(256)
void split_convert(const float* __restrict__ src, int srcld, int validR,
                   _Float16* __restrict__ dhi, _Float16* __restrict__ dlo,
                   int dstld, int coloff, int R, int C, int gperm)
{
    const int total = R * C;
    for (int i = blockIdx.x * 256 + threadIdx.x; i < total; i += gridDim.x * 256) {
        const int r = i / C, c = i % C;
        int dr = r;
        if (gperm) {
            const int gate = r >> 9, h = r & 511;
            dr = ((h >> 4) << 6) + (gate << 4) + (h & 15);
        }
        const float v = (r < validR) ? src[(size_t)r * srcld + c] : 0.f;
        wsplit(dhi, dlo, (size_t)dr * dstld + coloff + c, v);
    }
}

// init: A1[0] = [E[BOS]|0], A1[1] = 0, A2[0] = A2[1] = 0, c1 = c2 = 0
__global__ __launch_bounds__(256)
void init_kernel(_Float16* __restrict__ a1h0, _Float16* __restrict__ a1l0,
                 _Float16* __restrict__ a1h1, _Float16* __restrict__ a1l1,
                 _Float16* __restrict__ a2h0, _Float16* __restrict__ a2l0,
                 _Float16* __restrict__ a2h1, _Float16* __restrict__ a2l1,
                 float* __restrict__ c1, float* __restrict__ c2,
                 const float* __restrict__ E)
{
    const int idx = blockIdx.x * 256 + threadIdx.x;   // grid covers 512*1536
    if (idx < Bsz * K1) {
        const int col = idx % K1;
        const float v = (col < Em) ? E[(size_t)BOS * Em + col] : 0.f;
        wsplit(a1h0, a1l0, idx, v);
        wsplit(a1h1, a1l1, idx, 0.f);
    }
    if (idx < Bsz * K2) {
        wsplit(a2h0, a2l0, idx, 0.f);
        wsplit(a2h1, a2l1, idx, 0.f);
    }
    if (idx < Bsz * Hh) { c1[idx] = 0.f; c2[idx] = 0.f; }
}

// f_mean (fp32 + split pair)
__global__ __launch_bounds__(256)
void fmean_kernel(const float* __restrict__ f_att, float* __restrict__ f_mean,
                  _Float16* __restrict__ fmh, _Float16* __restrict__ fml)
{
    const int b = blockIdx.x;
    for (int a = threadIdx.x; a < Aa; a += 256) {
        float s = 0.f;
        for (int k = 0; k < Kf; ++k) s += f_att[((size_t)b * Kf + k) * Aa + a];
        const float v = s * (1.0f / 36.0f);
        f_mean[(size_t)b * Aa + a] = v;
        wsplit(fmh, fml, (size_t)b * Aa + a, v);
    }
}

// Fused attention: e scores (tanh dot with GEMM-produced q), softmax over k,
// ctx -> A2 cols [512,1024). One block per b.
__global__ __launch_bounds__(256)
void attn_fused(const float* __restrict__ att_f, const float* __restrict__ q,
                const float* __restrict__ wa2, const float* __restrict__ ba2,
                const float* __restrict__ f_att,
                _Float16* __restrict__ a2h, _Float16* __restrict__ a2l)
{
    const int b = blockIdx.x, tid = threadIdx.x;
    const int w = tid >> 6, lane = tid & 63;
    __shared__ float se[Kf];
    __shared__ float wk[Kf];
    const float* pq = q + (size_t)b * Aa;
    for (int k = w; k < Kf; k += 4) {
        const float* pf = att_f + ((size_t)b * Kf + k) * Aa;
        float s = 0.f;
        #pragma unroll
        for (int j = 0; j < Aa; j += 64) {
            const int a = j + lane;
            s += tanhf(pf[a] + pq[a]) * wa2[a];
        }
        #pragma unroll
        for (int off = 32; off; off >>= 1) s += __shfl_down(s, off);
        if (lane == 0) se[k] = s + ba2[0];
    }
    __syncthreads();
    if (tid < Kf) {
        float mx = -INFINITY;
        for (int k = 0; k < Kf; ++k) mx = fmaxf(mx, se[k]);
        float ssum = 0.f;
        for (int k = 0; k < Kf; ++k) ssum += expf(se[k] - mx);
        wk[tid] = expf(se[tid] - mx) / ssum;
    }
    __syncthreads();
    for (int a = tid; a < Aa; a += 256) {
        float acc = 0.f;
        for (int k = 0; k < Kf; ++k)
            acc = fmaf(wk[k], f_att[((size_t)b * Kf + k) * Aa + a], acc);
        wsplit(a2h, a2l, (size_t)b * K2 + Hh + a, acc);
    }
}

// final argmax over per-tile candidates + embed gather -> A1_nxt cols [0,300)
__global__ __launch_bounds__(256)
void argmax_embed_kernel(const float* __restrict__ candV, const int* __restrict__ candI,
                         const float* __restrict__ E,
                         _Float16* __restrict__ a1h, _Float16* __restrict__ a1l,
                         int* __restrict__ out, int t, int ntl)
{
    const int b = blockIdx.x;
    const int tid = threadIdx.x;
    __shared__ float sv[256];
    __shared__ int   si[256];
    float bvv = -INFINITY; int bii = 0x7fffffff;
    if (tid < ntl) { bvv = candV[(size_t)b * ntl + tid]; bii = candI[(size_t)b * ntl + tid]; }
    sv[tid] = bvv; si[tid] = bii;
    __syncthreads();
    for (int s = 128; s > 0; s >>= 1) {
        if (tid < s) {
            const float v2 = sv[tid + s];
            const int   i2 = si[tid + s];
            if (v2 > sv[tid] || (v2 == sv[tid] && i2 < si[tid])) { sv[tid] = v2; si[tid] = i2; }
        }
        __syncthreads();
    }
    const int idx = si[0];
    if (tid == 0) out[(size_t)b * TSTEPS + t] = idx;
    for (int d = tid; d < Em; d += 256)
        wsplit(a1h, a1l, (size_t)b * K1 + d, E[(size_t)idx * Em + d]);
}

// ============================================================
// host side
// ============================================================
static inline void conv(hipStream_t s, const float* src, int srcld, int validR,
                        _Float16* dhi, _Float16* dlo, int dstld, int coloff,
                        int R, int C, int gperm)
{
    int blocks = CDIV(R * C, 256); if (blocks > 2048) blocks = 2048;
    split_convert<<<dim3(blocks), dim3(256), 0, s>>>(src, srcld, validR, dhi, dlo,
                                                     dstld, coloff, R, C, gperm);
}

extern "C" void kernel_launch(void* const* d_in, const int* in_sizes, int n_in,
                              void* d_out, int out_size, void* d_ws, size_t ws_size,
                              hipStream_t stream)
{
    const float* feats = (const float*)d_in[0];
    const float* Wp    = (const float*)d_in[1];
    const float* bp    = (const float*)d_in[2];
    const float* E     = (const float*)d_in[3];
    const float* Wih1  = (const float*)d_in[4];
    const float* Whh1  = (const float*)d_in[5];
    const float* bih1  = (const float*)d_in[6];
    const float* bhh1  = (const float*)d_in[7];
    const float* Wih2  = (const float*)d_in[8];
    const float* Whh2  = (const float*)d_in[9];
    const float* bih2  = (const float*)d_in[10];
    const float* bhh2  = (const float*)d_in[11];
    const float* Wa1   = (const float*)d_in[12];
    const float* ba1   = (const float*)d_in[13];
    const float* wa2   = (const float*)d_in[14];
    const float* ba2   = (const float*)d_in[15];
    const float* Wo    = (const float*)d_in[16];
    const float* bo    = (const float*)d_in[17];
    int* out = (int*)d_out;
    (void)in_sizes; (void)n_in; (void)out_size; (void)ws_size;

    uint8_t* w = (uint8_t*)d_ws;
    size_t off = 0;
    auto alloc = [&](size_t bytes) { void* p = w + off; off = (off + bytes + 255) & ~(size_t)255; return p; };

    float*     f_att  = (float*)alloc(18432ull * 512 * 4);
    float*     att_f  = (float*)alloc(18432ull * 512 * 4);
    float*     f_mean = (float*)alloc(512ull * 512 * 4);
    _Float16*  fmh    = (_Float16*)alloc(512ull * 512 * 2);
    _Float16*  fml    = (_Float16*)alloc(512ull * 512 * 2);
    _Float16*  wph    = (_Float16*)alloc(512ull * 2048 * 2);
    _Float16*  wpl    = (_Float16*)alloc(512ull * 2048 * 2);
    _Float16*  w1ph   = (_Float16*)alloc(2048ull * K1 * 2);
    _Float16*  w1pl   = (_Float16*)alloc(2048ull * K1 * 2);
    _Float16*  w1ch   = (_Float16*)alloc(2048ull * 512 * 2);
    _Float16*  w1cl   = (_Float16*)alloc(2048ull * 512 * 2);
    _Float16*  w2ph   = (_Float16*)alloc(2048ull * K2 * 2);
    _Float16*  w2pl   = (_Float16*)alloc(2048ull * K2 * 2);
    _Float16*  wahh   = (_Float16*)alloc(512ull * 512 * 2);
    _Float16*  wahl   = (_Float16*)alloc(512ull * 512 * 2);
    _Float16*  wafh   = (_Float16*)alloc(512ull * 512 * 2);
    _Float16*  wafl   = (_Float16*)alloc(512ull * 512 * 2);
    _Float16*  woh    = (_Float16*)alloc((size_t)VvP * 512 * 2);
    _Float16*  wol    = (_Float16*)alloc((size_t)VvP * 512 * 2);
    float*     g1c    = (float*)alloc(512ull * 2048 * 4);
    _Float16*  a1h[2] = {(_Float16*)alloc(512ull * K1 * 2), (_Float16*)alloc(512ull * K1 * 2)};
    _Float16*  a1l[2] = {(_Float16*)alloc(512ull * K1 * 2), (_Float16*)alloc(512ull * K1 * 2)};
    _Float16*  a2h[2] = {(_Float16*)alloc(512ull * K2 * 2), (_Float16*)alloc(512ull * K2 * 2)};
    _Float16*  a2l[2] = {(_Float16*)alloc(512ull * K2 * 2), (_Float16*)alloc(512ull * K2 * 2)};
    float*     c1     = (float*)alloc(512ull * 512 * 4);
    float*     c2     = (float*)alloc(512ull * 512 * 4);
    float*     qbuf   = (float*)alloc(512ull * 512 * 4);
    float*     candV  = (float*)alloc(512ull * NTL * 4);
    int*       candI  = (int*)alloc(512ull * NTL * 4);

    // ---- weight conversions (g1/g2 weights gate-interleaved) ----
    conv(stream, Wp,        Dd,      512,  wph,  wpl,  2048, 0,    512,  2048, 0);
    conv(stream, Wih1,      Em + Aa, 2048, w1ph, w1pl, K1,   0,    2048, Em,   1);
    conv(stream, Whh1,      Hh,      2048, w1ph, w1pl, K1,   Em,   2048, 512,  1);
    conv(stream, Wih1,      Em + Aa, 0,    w1ph, w1pl, K1,   812,  2048, 20,   1);  // zero pad
    conv(stream, Wih1 + Em, Em + Aa, 2048, w1ch, w1cl, 512,  0,    2048, 512,  1);
    conv(stream, Wih2,      Hh + Aa, 2048, w2ph, w2pl, K2,   0,    2048, 1024, 1);
    conv(stream, Whh2,      Hh,      2048, w2ph, w2pl, K2,   1024, 2048, 512,  1);
    conv(stream, Wa1,       Hh + Aa, 512,  wahh, wahl, 512,  0,    512,  512,  0);
    conv(stream, Wa1 + Hh,  Hh + Aa, 512,  wafh, wafl, 512,  0,    512,  512,  0);
    conv(stream, Wo,        Hh,      Vv,   woh,  wol,  512,  0,    VvP,  512,  0);

    init_kernel<<<dim3(CDIV(Bsz * K2, 256)), dim3(256), 0, stream>>>(
        a1h[0], a1l[0], a1h[1], a1l[1], a2h[0], a2l[0], a2h[1], a2l[1], c1, c2, E);

    // ---- precompute (512-thread AF32 GEMMs; values bit-identical to r7) ----
    gemm_af32<<<dim3(1152), dim3(512), 0, stream>>>(
        feats, Dd, wph, wpl, 2048, f_att, 512, 512, 2048, bp, 8);
    fmean_kernel<<<dim3(Bsz), dim3(256), 0, stream>>>(f_att, f_mean, fmh, fml);
    // g1c = f_mean @ W1c^T + bih1 + bhh1  (permuted cols, EPI1 bias remap)
    gemm_sp<64, 64, 64, 2, 1, 1><<<dim3(32, 8), 256, 0, stream>>>(
        fmh, fml, 512, w1ch, w1cl, 512, g1c, 2048, 2048, 512,
        bih1, bhh1, nullptr,
        nullptr, nullptr, nullptr, 0, 0, nullptr, nullptr, 0, 0, nullptr, nullptr, 0);
    gemm_af32<<<dim3(1152), dim3(512), 0, stream>>>(
        f_att, 512, wafh, wafl, 512, att_f, 512, 512, 512, ba1, 8);

    // ---- decode loop (6 launches/step; ping-pong A1/A2; BK=64 EPI2) ----
    for (int t = 0; t < TSTEPS; ++t) {
        const int cur = t & 1, nxt = cur ^ 1;
        // g1 GEMM (K=832) + LSTM1 epilogue: reads A1[cur]; h1 -> A2[cur][0,512)
        // and A1[nxt][300,812); c1 in-place. addC = g1c (permuted, biases incl).
        gemm_sp<64, 64, 64, 4, 2, 2><<<dim3(32, 8), 256, 0, stream>>>(
            a1h[cur], a1l[cur], K1, w1ph, w1pl, K1, nullptr, 2048, 2048, K1,
            nullptr, nullptr, g1c,
            c1, a2h[cur], a2l[cur], K2, 0, a1h[nxt], a1l[nxt], K1, Em,
            nullptr, nullptr, 0);
        // q = h1 @ Wa1[:,:H]^T   (512 x 512, K=512)
        gemm_sp<64, 64, 64, 2, 1, 0><<<dim3(8, 8), 256, 0, stream>>>(
            a2h[cur], a2l[cur], K2, wahh, wahl, 512, qbuf, 512, 512, 512,
            nullptr, nullptr, nullptr,
            nullptr, nullptr, nullptr, 0, 0, nullptr, nullptr, 0, 0, nullptr, nullptr, 0);
        attn_fused<<<dim3(Bsz), dim3(256), 0, stream>>>(
            att_f, qbuf, wa2, ba2, f_att, a2h[cur], a2l[cur]);
        // g2 GEMM (K=1536) + LSTM2 epilogue: reads A2[cur]; h2 -> A2[nxt][1024,1536)
        gemm_sp<64, 64, 64, 4, 2, 2><<<dim3(32, 8), 256, 0, stream>>>(
            a2h[cur], a2l[cur], K2, w2ph, w2pl, K2, nullptr, 2048, 2048, K2,
            bih2, bhh2, nullptr,
            c2, a2h[nxt], a2l[nxt], K2, 1024, nullptr, nullptr, 0, 0,
            nullptr, nullptr, 0);
        // logits GEMM + per-tile argmax epilogue (h2 = A2[nxt] cols [1024,1536))
        gemm_sp<64, 64, 64, 2, 1, 3><<<dim3(NTL, 8), 256, 0, stream>>>(
            a2h[nxt] + 1024, a2l[nxt] + 1024, K2, woh, wol, 512, nullptr, 0, Vv, 512,
            bo, nullptr, nullptr,
            nullptr, nullptr, nullptr, 0, 0, nullptr, nullptr, 0, 0, candV, candI, NTL);
        argmax_embed_kernel<<<dim3(Bsz), dim3(256), 0, stream>>>(
            candV, candI, E, a1h[nxt], a1l[nxt], out, t, NTL);
    }
}